// Round 2
// baseline (590.360 us; speedup 1.0000x reference)
//
#include <hip/hip_runtime.h>

#define AS1 __attribute__((address_space(1)))
#define AS3 __attribute__((address_space(3)))

typedef __bf16 bf16;
typedef __bf16 bf16x8 __attribute__((ext_vector_type(8)));
typedef float f32x4 __attribute__((ext_vector_type(4)));

__device__ __forceinline__ void gld_lds16(const bf16* g, bf16* l) {
    __builtin_amdgcn_global_load_lds((const AS1 void*)g, (AS3 void*)l, 16, 0, 0);
}

// ---------------- fp32 -> bf16 cast ----------------
__global__ void cvt4_kernel(const float4* __restrict__ in, ushort4* __restrict__ out, int n4) {
    const int i = blockIdx.x * 256 + threadIdx.x;
    if (i >= n4) return;
    const float4 v = in[i];
    ushort4 r;
    r.x = __builtin_bit_cast(unsigned short, (bf16)v.x);
    r.y = __builtin_bit_cast(unsigned short, (bf16)v.y);
    r.z = __builtin_bit_cast(unsigned short, (bf16)v.z);
    r.w = __builtin_bit_cast(unsigned short, (bf16)v.w);
    out[i] = r;
}

// ---------------- GEMM: C[M,N] = A[M,K] * W[N,K]^T (both row-major, K contiguous) ----------------
// 128x128 tile, BK=64, 256 threads (4 waves in 2x2), mfma 16x16x32 bf16.
template <bool OUTF32>
__global__ void gemm_bt_kernel(const bf16* __restrict__ A, const bf16* __restrict__ W,
                               void* __restrict__ Cout, int M, int N, int K) {
    __shared__ __align__(16) bf16 lds[2 * 128 * 64];   // A tile [128][64], then B tile [128][64]
    const int tn = blockIdx.x * 128;
    const int tm = blockIdx.y * 128;
    const int tid = threadIdx.x;
    const int wave = tid >> 6;
    const int lane = tid & 63;
    const int wm = (wave >> 1) * 64;
    const int wn = (wave & 1) * 64;
    const int laneR = lane & 15;
    const int laneK = (lane >> 4) * 8;

    f32x4 acc[4][4] = {};

    for (int k0 = 0; k0 < K; k0 += 64) {
        // stage 32KB: 8 issues/wave x 64 lanes x 16B
#pragma unroll
        for (int iss = 0; iss < 8; ++iss) {
            const int Lb = iss * 4096 + wave * 1024;   // wave-uniform LDS byte base
            const int off = Lb + lane * 16;
            const bf16* g;
            if (off < 16384) {                 // A region: row stride 128B (64 bf16)
                const int row = off >> 7;
                const int cb = off & 127;
                g = A + (size_t)(tm + row) * K + (k0 + (cb >> 1));
            } else {                           // B region
                const int o2 = off - 16384;
                const int row = o2 >> 7;
                const int cb = o2 & 127;
                g = W + (size_t)(tn + row) * K + (k0 + (cb >> 1));
            }
            gld_lds16(g, (bf16*)((char*)lds + Lb));
        }
        __syncthreads();

        const bf16* ldsA = lds;
        const bf16* ldsB = lds + 128 * 64;
#pragma unroll
        for (int ks = 0; ks < 2; ++ks) {
            bf16x8 af[4], bfr[4];
#pragma unroll
            for (int i = 0; i < 4; ++i) {
                af[i]  = *(const bf16x8*)(ldsA + (wm + i * 16 + laneR) * 64 + ks * 32 + laneK);
                bfr[i] = *(const bf16x8*)(ldsB + (wn + i * 16 + laneR) * 64 + ks * 32 + laneK);
            }
#pragma unroll
            for (int i = 0; i < 4; ++i)
#pragma unroll
                for (int j = 0; j < 4; ++j)
                    acc[i][j] = __builtin_amdgcn_mfma_f32_16x16x32_bf16(af[i], bfr[j], acc[i][j], 0, 0, 0);
        }
        __syncthreads();
    }

    // epilogue: C/D layout col=lane&15, row=(lane>>4)*4+r
    const int rbase = (lane >> 4) * 4;
#pragma unroll
    for (int i = 0; i < 4; ++i) {
#pragma unroll
        for (int j = 0; j < 4; ++j) {
#pragma unroll
            for (int r = 0; r < 4; ++r) {
                const size_t row = (size_t)tm + wm + i * 16 + rbase + r;
                const size_t col = (size_t)tn + wn + j * 16 + laneR;
                if (OUTF32) ((float*)Cout)[row * N + col] = acc[i][j][r];
                else        ((bf16*)Cout)[row * N + col] = (bf16)acc[i][j][r];
            }
        }
    }
}

// ---------------- RoPE on q (pre-scaled by log2e/sqrt(D)) and k; layout -> [h][s][d] ----------------
// C_qkv [2048][6144] bf16: cols 0..4095 q, 4096..5119 k, 5120..6143 v
// q is scaled by (1/sqrt(128)) * log2(e) so the flash kernel can use exp2.
__global__ void rope_qk_kernel(const bf16* __restrict__ C, bf16* __restrict__ Qr, bf16* __restrict__ Kr) {
    const int idx = blockIdx.x * 256 + threadIdx.x;
    const int NQ = 2048 * 32 * 64;
    const float QSC = 0.12751743561884394f;        // (1/sqrt(128)) * log2(e)
    const float LN1E4_64 = 0.14391156831212787f;   // ln(10000)/64
    if (idx < NQ) {
        const int f = idx & 63;
        const int t = idx >> 6;
        const int h = t & 31;
        const int s = t >> 5;
        const float x1 = (float)C[(size_t)s * 6144 + h * 128 + f];
        const float x2 = (float)C[(size_t)s * 6144 + h * 128 + f + 64];
        const float th = s * expf(-LN1E4_64 * (float)f);
        const float cs = cosf(th), sn = sinf(th);
        bf16* dst = Qr + ((size_t)h * 2048 + s) * 128 + f;
        dst[0]  = (bf16)((x1 * cs - x2 * sn) * QSC);
        dst[64] = (bf16)((x2 * cs + x1 * sn) * QSC);
    } else {
        const int i2 = idx - NQ;
        const int f = i2 & 63;
        const int t = i2 >> 6;
        const int h = t & 7;
        const int s = t >> 3;
        const float x1 = (float)C[(size_t)s * 6144 + 4096 + h * 128 + f];
        const float x2 = (float)C[(size_t)s * 6144 + 4096 + h * 128 + f + 64];
        const float th = s * expf(-LN1E4_64 * (float)f);
        const float cs = cosf(th), sn = sinf(th);
        bf16* dst = Kr + ((size_t)h * 2048 + s) * 128 + f;
        dst[0]  = (bf16)(x1 * cs - x2 * sn);
        dst[64] = (bf16)(x2 * cs + x1 * sn);
    }
}

// ---------------- V transpose: C_qkv v-cols -> Vt[hkv][d=128][s=2048] ----------------
__global__ void transpose_v_kernel(const bf16* __restrict__ C, bf16* __restrict__ Vt) {
    __shared__ __align__(16) unsigned short t[64][136];
    const int hkv = blockIdx.x >> 5;
    const int st = blockIdx.x & 31;
    const int s0 = st * 64;
    const int tid = threadIdx.x;
#pragma unroll
    for (int it = 0; it < 4; ++it) {
        const int l = it * 2048 + tid * 8;   // elem index in [64][128]
        const int r = l >> 7, c = l & 127;
        *(bf16x8*)&t[r][c] = *(const bf16x8*)&C[(size_t)(s0 + r) * 6144 + 5120 + hkv * 128 + c];
    }
    __syncthreads();
#pragma unroll
    for (int it = 0; it < 8; ++it) {
        const int o = it * 1024 + tid * 4;   // out elem index in [128 d][64 s]
        const int d = o >> 6, j = o & 63;
        ushort4 pk;
        pk.x = t[j + 0][d];
        pk.y = t[j + 1][d];
        pk.z = t[j + 2][d];
        pk.w = t[j + 3][d];
        *(ushort4*)&Vt[((size_t)hkv * 128 + d) * 2048 + s0 + j] = pk;
    }
}

// ---------------- causal GQA flash attention, barrier-free ----------------
// 1 block = 1 wave = (head h, 32 q rows). KV tile = 128, K/V fragments read
// DIRECTLY from global (L1/L2-resident; K+V = 1MB per hkv head fits per-XCD L2).
// Only LDS use: wave-private P transpose buffer (8KB), XOR-swizzled.
// bid&7 = hkv so round-robin dispatch keeps each hkv group on one XCD.
__launch_bounds__(64, 2)
__global__ void flash_attn_kernel(const bf16* __restrict__ Qr, const bf16* __restrict__ Kr,
                                  const bf16* __restrict__ Vt, bf16* __restrict__ Aout) {
    __shared__ __align__(16) char Plds[32 * 256];   // [32 q rows][256B], swizzled
    const int bid = blockIdx.x;
    const int hkv = bid & 7;
    const int r = bid >> 3;
    const int h = hkv * 4 + (r & 3);
    const int qb = 63 - (r >> 2);         // heavy blocks first
    const int q0 = qb * 32;
    const int lane = threadIdx.x;
    const int laneR = lane & 15;
    const int laneS = lane >> 4;          // 0..3
    const int laneK = laneS * 8;
    const int rbase = laneS * 4;

    const bf16* Kh = Kr + (size_t)hkv * 2048 * 128;
    const bf16* Vh = Vt + (size_t)hkv * 128 * 2048;

    // Q fragments (pre-scaled by log2e/sqrt(D))
    bf16x8 qf[2][4];
#pragma unroll
    for (int mi = 0; mi < 2; ++mi)
#pragma unroll
        for (int kc = 0; kc < 4; ++kc)
            qf[mi][kc] = *(const bf16x8*)&Qr[((size_t)h * 2048 + q0 + mi * 16 + laneR) * 128 + kc * 32 + laneK];

    f32x4 o[2][8] = {};
    float mrow[2][4], lrow[2][4];
#pragma unroll
    for (int mi = 0; mi < 2; ++mi)
#pragma unroll
        for (int rr = 0; rr < 4; ++rr) { mrow[mi][rr] = -1e30f; lrow[mi][rr] = 0.f; }

    const int Tq = q0 >> 7;
    for (int t = 0; t <= Tq; ++t) {
        const int kv0 = t * 128;

        // ---- scores = Q K^T (log2 domain) ----
        f32x4 sc[2][8] = {};
#pragma unroll
        for (int kc = 0; kc < 4; ++kc) {
            bf16x8 kf[8];
#pragma unroll
            for (int j = 0; j < 8; ++j)
                kf[j] = *(const bf16x8*)&Kh[(size_t)(kv0 + j * 16 + laneR) * 128 + kc * 32 + laneK];
#pragma unroll
            for (int mi = 0; mi < 2; ++mi)
#pragma unroll
                for (int j = 0; j < 8; ++j)
                    sc[mi][j] = __builtin_amdgcn_mfma_f32_16x16x32_bf16(qf[mi][kc], kf[j], sc[mi][j], 0, 0, 0);
        }

        if (t == Tq) {  // diagonal tile: causal mask (global indices)
#pragma unroll
            for (int mi = 0; mi < 2; ++mi)
#pragma unroll
                for (int j = 0; j < 8; ++j)
#pragma unroll
                    for (int rr = 0; rr < 4; ++rr) {
                        const int qr = q0 + mi * 16 + rbase + rr;
                        const int kr = kv0 + j * 16 + laneR;
                        if (kr > qr) sc[mi][j][rr] = -1e30f;
                    }
        }

        // ---- online softmax (rows live in 16 lanes; reduce via shfl_xor 1/2/4/8) ----
#pragma unroll
        for (int mi = 0; mi < 2; ++mi) {
#pragma unroll
            for (int rr = 0; rr < 4; ++rr) {
                float v = sc[mi][0][rr];
#pragma unroll
                for (int j = 1; j < 8; ++j) v = fmaxf(v, sc[mi][j][rr]);
                v = fmaxf(v, __shfl_xor(v, 1, 64));
                v = fmaxf(v, __shfl_xor(v, 2, 64));
                v = fmaxf(v, __shfl_xor(v, 4, 64));
                v = fmaxf(v, __shfl_xor(v, 8, 64));
                const float mnew = fmaxf(mrow[mi][rr], v);
                const float fac = exp2f(mrow[mi][rr] - mnew);
                mrow[mi][rr] = mnew;
                float rs = 0.f;
#pragma unroll
                for (int j = 0; j < 8; ++j) {
                    const float p = exp2f(sc[mi][j][rr] - mnew);
                    sc[mi][j][rr] = p;
                    rs += p;
                }
                rs += __shfl_xor(rs, 1, 64);
                rs += __shfl_xor(rs, 2, 64);
                rs += __shfl_xor(rs, 4, 64);
                rs += __shfl_xor(rs, 8, 64);
                lrow[mi][rr] = lrow[mi][rr] * fac + rs;
#pragma unroll
                for (int j = 0; j < 8; ++j) o[mi][j][rr] *= fac;
            }
        }

        // ---- write P into swizzled LDS (wave-private; no barrier needed) ----
#pragma unroll
        for (int mi = 0; mi < 2; ++mi)
#pragma unroll
            for (int j = 0; j < 8; ++j)
#pragma unroll
                for (int rr = 0; rr < 4; ++rr) {
                    const int row = mi * 16 + rbase + rr;
                    int byte = (row << 8) + (j << 5) + (laneR << 1);
                    byte ^= (row & 7) << 4;
                    *(bf16*)(Plds + byte) = (bf16)sc[mi][j][rr];
                }

        // ---- O += P V ----
#pragma unroll
        for (int kc = 0; kc < 4; ++kc) {
            bf16x8 pf[2], vf[8];
#pragma unroll
            for (int mi = 0; mi < 2; ++mi) {
                const int row = mi * 16 + laneR;
                int cb = (kc << 6) + (laneS << 4);
                cb ^= (row & 7) << 4;
                pf[mi] = *(const bf16x8*)(Plds + (row << 8) + cb);
            }
#pragma unroll
            for (int j = 0; j < 8; ++j)
                vf[j] = *(const bf16x8*)&Vh[(size_t)(j * 16 + laneR) * 2048 + kv0 + kc * 32 + laneK];
#pragma unroll
            for (int mi = 0; mi < 2; ++mi)
#pragma unroll
                for (int j = 0; j < 8; ++j)
                    o[mi][j] = __builtin_amdgcn_mfma_f32_16x16x32_bf16(pf[mi], vf[j], o[mi][j], 0, 0, 0);
        }
    }

    // ---- normalize + write attn output [s][h*128+d] ----
#pragma unroll
    for (int mi = 0; mi < 2; ++mi) {
        float rinv[4];
#pragma unroll
        for (int rr = 0; rr < 4; ++rr) rinv[rr] = 1.0f / lrow[mi][rr];
#pragma unroll
        for (int j = 0; j < 8; ++j)
#pragma unroll
            for (int rr = 0; rr < 4; ++rr) {
                const size_t row = (size_t)q0 + mi * 16 + rbase + rr;
                Aout[row * 4096 + h * 128 + j * 16 + laneR] = (bf16)(o[mi][j][rr] * rinv[rr]);
            }
    }
}

// ---------------- launch ----------------
extern "C" void kernel_launch(void* const* d_in, const int* in_sizes, int n_in,
                              void* d_out, int out_size, void* d_ws, size_t ws_size,
                              hipStream_t stream) {
    const float* hidden = (const float*)d_in[0];
    const float* Wq = (const float*)d_in[1];
    const float* Wk = (const float*)d_in[2];
    const float* Wv = (const float*)d_in[3];
    const float* Wo = (const float*)d_in[4];
    float* out = (float*)d_out;
    char* ws = (char*)d_ws;

    // workspace layout (bytes):
    bf16* hs = (bf16*)(ws + 0);                 // [2048][4096]        16 MiB
    bf16* Wb = (bf16*)(ws + 16777216);          // [10240][4096]       80 MiB (Wq|Wk|Wv|Wo)
    bf16* Cq = (bf16*)(ws + 100663296);         // [2048][6144]        24 MiB
    bf16* Qr = (bf16*)(ws + 125829120);         // [32][2048][128]     16 MiB
    bf16* Kr = (bf16*)(ws + 142606336);         // [8][2048][128]       4 MiB
    bf16* Vt = (bf16*)(ws + 146800640);         // [8][128][2048]       4 MiB
    bf16* At = (bf16*)(ws + 150994944);         // [2048][4096]        16 MiB
    (void)ws_size; (void)in_sizes; (void)n_in; (void)out_size;

    // 1. casts
    cvt4_kernel<<<8192, 256, 0, stream>>>((const float4*)hidden, (ushort4*)hs, 2097152);
    cvt4_kernel<<<16384, 256, 0, stream>>>((const float4*)Wq, (ushort4*)(Wb + 0), 4194304);
    cvt4_kernel<<<4096, 256, 0, stream>>>((const float4*)Wk, (ushort4*)(Wb + 16777216), 1048576);
    cvt4_kernel<<<4096, 256, 0, stream>>>((const float4*)Wv, (ushort4*)(Wb + 20971520), 1048576);
    cvt4_kernel<<<16384, 256, 0, stream>>>((const float4*)Wo, (ushort4*)(Wb + 25165824), 4194304);

    // 2. fused QKV projection: [2048,6144] = hs @ Wqkv^T
    gemm_bt_kernel<false><<<dim3(48, 16), 256, 0, stream>>>(hs, Wb, Cq, 2048, 6144, 4096);

    // 3. RoPE (+transpose to [h][s][d]); q pre-scaled by log2e/sqrt(D)
    rope_qk_kernel<<<20480, 256, 0, stream>>>(Cq, Qr, Kr);

    // 4. V transpose -> [hkv][d][s]
    transpose_v_kernel<<<256, 256, 0, stream>>>(Cq, Vt);

    // 5. causal GQA flash attention -> At [2048][4096] bf16 (1 wave per 32 q-rows)
    flash_attn_kernel<<<2048, 64, 0, stream>>>(Qr, Kr, Vt, At);

    // 6. output projection: out = At @ Wo^T (fp32 out)
    gemm_bt_kernel<true><<<dim3(32, 16), 256, 0, stream>>>(At, Wb + 25165824, out, 2048, 4096, 4096);
}

// Round 4
// 419.037 us; speedup vs baseline: 1.4088x; 1.4088x over previous
//
#include <hip/hip_runtime.h>

#define AS1 __attribute__((address_space(1)))
#define AS3 __attribute__((address_space(3)))

typedef __bf16 bf16;
typedef __bf16 bf16x8 __attribute__((ext_vector_type(8)));
typedef float f32x4 __attribute__((ext_vector_type(4)));

__device__ __forceinline__ void gld_lds16(const bf16* g, bf16* l) {
    __builtin_amdgcn_global_load_lds((const AS1 void*)g, (AS3 void*)l, 16, 0, 0);
}

// ---------------- fp32 -> bf16 cast ----------------
__global__ void cvt4_kernel(const float4* __restrict__ in, ushort4* __restrict__ out, int n4) {
    const int i = blockIdx.x * 256 + threadIdx.x;
    if (i >= n4) return;
    const float4 v = in[i];
    ushort4 r;
    r.x = __builtin_bit_cast(unsigned short, (bf16)v.x);
    r.y = __builtin_bit_cast(unsigned short, (bf16)v.y);
    r.z = __builtin_bit_cast(unsigned short, (bf16)v.z);
    r.w = __builtin_bit_cast(unsigned short, (bf16)v.w);
    out[i] = r;
}

// ---------------- GEMM: C[M,N] = A[M,K] * W[N,K]^T (both row-major, K contiguous) ----------------
// 128x128 tile, BK=64, 256 threads (4 waves in 2x2), mfma 16x16x32 bf16.
template <bool OUTF32>
__global__ void gemm_bt_kernel(const bf16* __restrict__ A, const bf16* __restrict__ W,
                               void* __restrict__ Cout, int M, int N, int K) {
    __shared__ __align__(16) bf16 lds[2 * 128 * 64];   // A tile [128][64], then B tile [128][64]
    const int tn = blockIdx.x * 128;
    const int tm = blockIdx.y * 128;
    const int tid = threadIdx.x;
    const int wave = tid >> 6;
    const int lane = tid & 63;
    const int wm = (wave >> 1) * 64;
    const int wn = (wave & 1) * 64;
    const int laneR = lane & 15;
    const int laneK = (lane >> 4) * 8;

    f32x4 acc[4][4] = {};

    for (int k0 = 0; k0 < K; k0 += 64) {
        // stage 32KB: 8 issues/wave x 64 lanes x 16B
#pragma unroll
        for (int iss = 0; iss < 8; ++iss) {
            const int Lb = iss * 4096 + wave * 1024;   // wave-uniform LDS byte base
            const int off = Lb + lane * 16;
            const bf16* g;
            if (off < 16384) {                 // A region: row stride 128B (64 bf16)
                const int row = off >> 7;
                const int cb = off & 127;
                g = A + (size_t)(tm + row) * K + (k0 + (cb >> 1));
            } else {                           // B region
                const int o2 = off - 16384;
                const int row = o2 >> 7;
                const int cb = o2 & 127;
                g = W + (size_t)(tn + row) * K + (k0 + (cb >> 1));
            }
            gld_lds16(g, (bf16*)((char*)lds + Lb));
        }
        __syncthreads();

        const bf16* ldsA = lds;
        const bf16* ldsB = lds + 128 * 64;
#pragma unroll
        for (int ks = 0; ks < 2; ++ks) {
            bf16x8 af[4], bfr[4];
#pragma unroll
            for (int i = 0; i < 4; ++i) {
                af[i]  = *(const bf16x8*)(ldsA + (wm + i * 16 + laneR) * 64 + ks * 32 + laneK);
                bfr[i] = *(const bf16x8*)(ldsB + (wn + i * 16 + laneR) * 64 + ks * 32 + laneK);
            }
#pragma unroll
            for (int i = 0; i < 4; ++i)
#pragma unroll
                for (int j = 0; j < 4; ++j)
                    acc[i][j] = __builtin_amdgcn_mfma_f32_16x16x32_bf16(af[i], bfr[j], acc[i][j], 0, 0, 0);
        }
        __syncthreads();
    }

    // epilogue: C/D layout col=lane&15, row=(lane>>4)*4+r
    const int rbase = (lane >> 4) * 4;
#pragma unroll
    for (int i = 0; i < 4; ++i) {
#pragma unroll
        for (int j = 0; j < 4; ++j) {
#pragma unroll
            for (int r = 0; r < 4; ++r) {
                const size_t row = (size_t)tm + wm + i * 16 + rbase + r;
                const size_t col = (size_t)tn + wn + j * 16 + laneR;
                if (OUTF32) ((float*)Cout)[row * N + col] = acc[i][j][r];
                else        ((bf16*)Cout)[row * N + col] = (bf16)acc[i][j][r];
            }
        }
    }
}

// ---------------- RoPE on q (pre-scaled by log2e/sqrt(D)) and k; layout -> [h][s][d] ----------------
// C_qkv [2048][6144] bf16: cols 0..4095 q, 4096..5119 k, 5120..6143 v
// q is scaled by (1/sqrt(128)) * log2(e) so the flash kernel can use exp2.
__global__ void rope_qk_kernel(const bf16* __restrict__ C, bf16* __restrict__ Qr, bf16* __restrict__ Kr) {
    const int idx = blockIdx.x * 256 + threadIdx.x;
    const int NQ = 2048 * 32 * 64;
    const float QSC = 0.12751743561884394f;        // (1/sqrt(128)) * log2(e)
    const float LN1E4_64 = 0.14391156831212787f;   // ln(10000)/64
    if (idx < NQ) {
        const int f = idx & 63;
        const int t = idx >> 6;
        const int h = t & 31;
        const int s = t >> 5;
        const float x1 = (float)C[(size_t)s * 6144 + h * 128 + f];
        const float x2 = (float)C[(size_t)s * 6144 + h * 128 + f + 64];
        const float th = s * expf(-LN1E4_64 * (float)f);
        const float cs = cosf(th), sn = sinf(th);
        bf16* dst = Qr + ((size_t)h * 2048 + s) * 128 + f;
        dst[0]  = (bf16)((x1 * cs - x2 * sn) * QSC);
        dst[64] = (bf16)((x2 * cs + x1 * sn) * QSC);
    } else {
        const int i2 = idx - NQ;
        const int f = i2 & 63;
        const int t = i2 >> 6;
        const int h = t & 7;
        const int s = t >> 3;
        const float x1 = (float)C[(size_t)s * 6144 + 4096 + h * 128 + f];
        const float x2 = (float)C[(size_t)s * 6144 + 4096 + h * 128 + f + 64];
        const float th = s * expf(-LN1E4_64 * (float)f);
        const float cs = cosf(th), sn = sinf(th);
        bf16* dst = Kr + ((size_t)h * 2048 + s) * 128 + f;
        dst[0]  = (bf16)(x1 * cs - x2 * sn);
        dst[64] = (bf16)(x2 * cs + x1 * sn);
    }
}

// ---------------- V transpose: C_qkv v-cols -> Vt[hkv][d=128][s=2048] ----------------
__global__ void transpose_v_kernel(const bf16* __restrict__ C, bf16* __restrict__ Vt) {
    __shared__ __align__(16) unsigned short t[64][136];
    const int hkv = blockIdx.x >> 5;
    const int st = blockIdx.x & 31;
    const int s0 = st * 64;
    const int tid = threadIdx.x;
#pragma unroll
    for (int it = 0; it < 4; ++it) {
        const int l = it * 2048 + tid * 8;   // elem index in [64][128]
        const int r = l >> 7, c = l & 127;
        *(bf16x8*)&t[r][c] = *(const bf16x8*)&C[(size_t)(s0 + r) * 6144 + 5120 + hkv * 128 + c];
    }
    __syncthreads();
#pragma unroll
    for (int it = 0; it < 8; ++it) {
        const int o = it * 1024 + tid * 4;   // out elem index in [128 d][64 s]
        const int d = o >> 6, j = o & 63;
        ushort4 pk;
        pk.x = t[j + 0][d];
        pk.y = t[j + 1][d];
        pk.z = t[j + 2][d];
        pk.w = t[j + 3][d];
        *(ushort4*)&Vt[((size_t)hkv * 128 + d) * 2048 + s0 + j] = pk;
    }
}

// ---------------- causal GQA flash attention, pipelined LDS staging ----------------
// Block = 4 waves (256 thr), each wave owns 32 q-rows -> 128 q-rows/block.
// KVBLK=64. K and V double-buffered in LDS via global_load_lds with PRE-SWIZZLED
// global source (LDS written linearly, XOR-swizzle applied on the global address
// and on the LDS read side -> all ds ops <=2-way conflicts). One barrier per tile:
//   issue gld_lds(t+1 -> buf^1); compute tile t from buf; __syncthreads (drains vmcnt).
// Mask predicate: tile needs masking iff its max kr (kv0+63) exceeds the wave's
// FIRST row (q0w); fully-masked tiles (kv0 > q0w+31) skip compute entirely
// (stage+barrier still run on all waves -> block-wide sync structure unchanged).
__launch_bounds__(256, 2)
__global__ void flash_attn_kernel(const bf16* __restrict__ Qr, const bf16* __restrict__ Kr,
                                  const bf16* __restrict__ Vt, bf16* __restrict__ Aout) {
    __shared__ __align__(16) bf16 Klds[2][64 * 128];    // [kv][d], swizzled, 2x16KB
    __shared__ __align__(16) bf16 Vlds[2][128 * 64];    // [d][kv], swizzled, 2x16KB
    __shared__ __align__(16) char Plds[4][4096];        // per-wave P [32][64] bf16, swizzled

    const int bid = blockIdx.x;
    const int hkv = bid & 7;
    const int r = bid >> 3;                 // 0..63
    const int h = hkv * 4 + (r & 3);
    const int qmi = r >> 2;                 // 0..15
    const int qb = (qmi < 8) ? (15 - qmi) : (qmi - 8);   // pair heavy with light per CU
    const int tid = threadIdx.x;
    const int wave = tid >> 6, lane = tid & 63;
    const int laneR = lane & 15;
    const int laneS = lane >> 4;
    const int laneK = laneS * 8;
    const int rbase = laneS * 4;
    const int q0w = qb * 128 + wave * 32;

    const bf16* Kh = Kr + (size_t)hkv * 2048 * 128;
    const bf16* Vh = Vt + (size_t)hkv * 128 * 2048;
    char* Pw = Plds[wave];

    // stage one KV tile (64 kv rows) into buffer `buf`; per-wave 4 K-chunks + 4 V-chunks of 1KB
    auto stageKV = [&](int t, int buf) {
        const int kv0 = t * 64;
#pragma unroll
        for (int s = 0; s < 4; ++s) {
            const int chunk = wave * 4 + s;
            const int L = chunk * 64 + lane;        // 16B-slot index
            const int krow = L >> 4, kc16 = L & 15; // K: 16 slots per 256B row
            gld_lds16(Kh + (size_t)(kv0 + krow) * 128 + ((kc16 ^ (krow & 7)) << 3),
                      &Klds[buf][chunk * 512]);
            const int vrow = L >> 3, vc8 = L & 7;   // V: 8 slots per 128B row
            gld_lds16(Vh + (size_t)vrow * 2048 + kv0 + ((vc8 ^ (vrow & 7)) << 3),
                      &Vlds[buf][chunk * 512]);
        }
    };

    // Q fragments (pre-scaled by log2e/sqrt(D))
    bf16x8 qf[2][4];
#pragma unroll
    for (int mi = 0; mi < 2; ++mi)
#pragma unroll
        for (int kc = 0; kc < 4; ++kc)
            qf[mi][kc] = *(const bf16x8*)&Qr[((size_t)h * 2048 + q0w + mi * 16 + laneR) * 128 + kc * 32 + laneK];

    f32x4 o[2][8] = {};
    float mrow[2][4], lrow[2][4];
#pragma unroll
    for (int mi = 0; mi < 2; ++mi)
#pragma unroll
        for (int rr = 0; rr < 4; ++rr) { mrow[mi][rr] = -1e30f; lrow[mi][rr] = 0.f; }

    const int ntiles = 2 * qb + 2;
    stageKV(0, 0);
    __syncthreads();

    for (int t = 0; t < ntiles; ++t) {
        const int cur = t & 1;
        const int kv0 = t * 64;
        if (t + 1 < ntiles) stageKV(t + 1, cur ^ 1);   // loads fly during compute

        if (kv0 <= q0w + 31) {   // tile has at least one unmasked entry for this wave
            // ---- scores = Q K^T (log2 domain) ----
            f32x4 sc[2][4] = {};
#pragma unroll
            for (int kc = 0; kc < 4; ++kc) {
                bf16x8 kf[4];
#pragma unroll
                for (int j = 0; j < 4; ++j) {
                    const int row = j * 16 + laneR;
                    kf[j] = *(const bf16x8*)((const char*)Klds[cur] + row * 256 +
                                             ((kc * 64 + laneS * 16) ^ ((row & 7) << 4)));
                }
#pragma unroll
                for (int mi = 0; mi < 2; ++mi)
#pragma unroll
                    for (int j = 0; j < 4; ++j)
                        sc[mi][j] = __builtin_amdgcn_mfma_f32_16x16x32_bf16(qf[mi][kc], kf[j], sc[mi][j], 0, 0, 0);
            }

            if (kv0 + 63 > q0w) {   // diagonal tile: causal mask (tile max kr > wave min qr)
#pragma unroll
                for (int mi = 0; mi < 2; ++mi)
#pragma unroll
                    for (int j = 0; j < 4; ++j)
#pragma unroll
                        for (int rr = 0; rr < 4; ++rr) {
                            const int qr = q0w + mi * 16 + rbase + rr;
                            const int kr = kv0 + j * 16 + laneR;
                            if (kr > qr) sc[mi][j][rr] = -1e30f;
                        }
            }

            // ---- online softmax (rows live in 16 lanes; reduce via shfl_xor 1/2/4/8) ----
#pragma unroll
            for (int mi = 0; mi < 2; ++mi) {
#pragma unroll
                for (int rr = 0; rr < 4; ++rr) {
                    float v = sc[mi][0][rr];
#pragma unroll
                    for (int j = 1; j < 4; ++j) v = fmaxf(v, sc[mi][j][rr]);
                    v = fmaxf(v, __shfl_xor(v, 1, 64));
                    v = fmaxf(v, __shfl_xor(v, 2, 64));
                    v = fmaxf(v, __shfl_xor(v, 4, 64));
                    v = fmaxf(v, __shfl_xor(v, 8, 64));
                    const float mnew = fmaxf(mrow[mi][rr], v);
                    const float fac = exp2f(mrow[mi][rr] - mnew);
                    mrow[mi][rr] = mnew;
                    float rs = 0.f;
#pragma unroll
                    for (int j = 0; j < 4; ++j) {
                        const float p = exp2f(sc[mi][j][rr] - mnew);
                        sc[mi][j][rr] = p;
                        rs += p;
                    }
                    rs += __shfl_xor(rs, 1, 64);
                    rs += __shfl_xor(rs, 2, 64);
                    rs += __shfl_xor(rs, 4, 64);
                    rs += __shfl_xor(rs, 8, 64);
                    lrow[mi][rr] = lrow[mi][rr] * fac + rs;
#pragma unroll
                    for (int j = 0; j < 8; ++j) o[mi][j][rr] *= fac;
                }
            }

            // ---- write P into swizzled wave-private LDS ----
#pragma unroll
            for (int mi = 0; mi < 2; ++mi)
#pragma unroll
                for (int j = 0; j < 4; ++j)
#pragma unroll
                    for (int rr = 0; rr < 4; ++rr) {
                        const int row = mi * 16 + rbase + rr;
                        *(bf16*)(Pw + row * 128 + ((j * 32 + laneR * 2) ^ ((row & 7) << 4))) =
                            (bf16)sc[mi][j][rr];
                    }

            // ---- O += P V ----
#pragma unroll
            for (int kc = 0; kc < 2; ++kc) {
                bf16x8 pf[2];
#pragma unroll
                for (int mi = 0; mi < 2; ++mi) {
                    const int row = mi * 16 + laneR;
                    pf[mi] = *(const bf16x8*)(Pw + row * 128 + ((kc * 64 + laneS * 16) ^ ((row & 7) << 4)));
                }
                bf16x8 vf[8];
#pragma unroll
                for (int j = 0; j < 8; ++j) {
                    const int row = j * 16 + laneR;
                    vf[j] = *(const bf16x8*)((const char*)Vlds[cur] + row * 128 +
                                             ((kc * 64 + laneS * 16) ^ ((row & 7) << 4)));
                }
#pragma unroll
                for (int mi = 0; mi < 2; ++mi)
#pragma unroll
                    for (int j = 0; j < 8; ++j)
                        o[mi][j] = __builtin_amdgcn_mfma_f32_16x16x32_bf16(pf[mi], vf[j], o[mi][j], 0, 0, 0);
            }
        }

        __syncthreads();   // drains vmcnt (t+1 staged) + all waves done with buf `cur`
    }

    // ---- normalize + write attn output [s][h*128+d] ----
#pragma unroll
    for (int mi = 0; mi < 2; ++mi) {
        float rinv[4];
#pragma unroll
        for (int rr = 0; rr < 4; ++rr) rinv[rr] = 1.0f / lrow[mi][rr];
#pragma unroll
        for (int j = 0; j < 8; ++j)
#pragma unroll
            for (int rr = 0; rr < 4; ++rr) {
                const size_t row = (size_t)q0w + mi * 16 + rbase + rr;
                Aout[row * 4096 + h * 128 + j * 16 + laneR] = (bf16)(o[mi][j][rr] * rinv[rr]);
            }
    }
}

// ---------------- launch ----------------
extern "C" void kernel_launch(void* const* d_in, const int* in_sizes, int n_in,
                              void* d_out, int out_size, void* d_ws, size_t ws_size,
                              hipStream_t stream) {
    const float* hidden = (const float*)d_in[0];
    const float* Wq = (const float*)d_in[1];
    const float* Wk = (const float*)d_in[2];
    const float* Wv = (const float*)d_in[3];
    const float* Wo = (const float*)d_in[4];
    float* out = (float*)d_out;
    char* ws = (char*)d_ws;

    // workspace layout (bytes):
    bf16* hs = (bf16*)(ws + 0);                 // [2048][4096]        16 MiB
    bf16* Wb = (bf16*)(ws + 16777216);          // [10240][4096]       80 MiB (Wq|Wk|Wv|Wo)
    bf16* Cq = (bf16*)(ws + 100663296);         // [2048][6144]        24 MiB
    bf16* Qr = (bf16*)(ws + 125829120);         // [32][2048][128]     16 MiB
    bf16* Kr = (bf16*)(ws + 142606336);         // [8][2048][128]       4 MiB
    bf16* Vt = (bf16*)(ws + 146800640);         // [8][128][2048]       4 MiB
    bf16* At = (bf16*)(ws + 150994944);         // [2048][4096]        16 MiB
    (void)ws_size; (void)in_sizes; (void)n_in; (void)out_size;

    // 1. casts
    cvt4_kernel<<<8192, 256, 0, stream>>>((const float4*)hidden, (ushort4*)hs, 2097152);
    cvt4_kernel<<<16384, 256, 0, stream>>>((const float4*)Wq, (ushort4*)(Wb + 0), 4194304);
    cvt4_kernel<<<4096, 256, 0, stream>>>((const float4*)Wk, (ushort4*)(Wb + 16777216), 1048576);
    cvt4_kernel<<<4096, 256, 0, stream>>>((const float4*)Wv, (ushort4*)(Wb + 20971520), 1048576);
    cvt4_kernel<<<16384, 256, 0, stream>>>((const float4*)Wo, (ushort4*)(Wb + 25165824), 4194304);

    // 2. fused QKV projection: [2048,6144] = hs @ Wqkv^T
    gemm_bt_kernel<false><<<dim3(48, 16), 256, 0, stream>>>(hs, Wb, Cq, 2048, 6144, 4096);

    // 3. RoPE (+transpose to [h][s][d]); q pre-scaled by log2e/sqrt(D)
    rope_qk_kernel<<<20480, 256, 0, stream>>>(Cq, Qr, Kr);

    // 4. V transpose -> [hkv][d][s]
    transpose_v_kernel<<<256, 256, 0, stream>>>(Cq, Vt);

    // 5. causal GQA flash attention -> At [2048][4096] bf16
    flash_attn_kernel<<<512, 256, 0, stream>>>(Qr, Kr, Vt, At);

    // 6. output projection: out = At @ Wo^T (fp32 out)
    gemm_bt_kernel<true><<<dim3(32, 16), 256, 0, stream>>>(At, Wb + 25165824, out, 2048, 4096, 4096);
}

// Round 5
// 415.688 us; speedup vs baseline: 1.4202x; 1.0081x over previous
//
#include <hip/hip_runtime.h>

#define AS1 __attribute__((address_space(1)))
#define AS3 __attribute__((address_space(3)))

typedef __bf16 bf16;
typedef __bf16 bf16x8 __attribute__((ext_vector_type(8)));
typedef float f32x4 __attribute__((ext_vector_type(4)));

__device__ __forceinline__ void gld_lds16(const bf16* g, bf16* l) {
    __builtin_amdgcn_global_load_lds((const AS1 void*)g, (AS3 void*)l, 16, 0, 0);
}

// ---------------- fp32 -> bf16 cast ----------------
__global__ void cvt4_kernel(const float4* __restrict__ in, ushort4* __restrict__ out, int n4) {
    const int i = blockIdx.x * 256 + threadIdx.x;
    if (i >= n4) return;
    const float4 v = in[i];
    ushort4 r;
    r.x = __builtin_bit_cast(unsigned short, (bf16)v.x);
    r.y = __builtin_bit_cast(unsigned short, (bf16)v.y);
    r.z = __builtin_bit_cast(unsigned short, (bf16)v.z);
    r.w = __builtin_bit_cast(unsigned short, (bf16)v.w);
    out[i] = r;
}

// ---------------- GEMM: C[M,N] = A[M,K] * W[N,K]^T (both row-major, K contiguous) ----------------
// 128x128 tile, BK=64, 256 threads (4 waves in 2x2), mfma 16x16x32 bf16.
template <bool OUTF32>
__global__ void gemm_bt_kernel(const bf16* __restrict__ A, const bf16* __restrict__ W,
                               void* __restrict__ Cout, int M, int N, int K) {
    __shared__ __align__(16) bf16 lds[2 * 128 * 64];   // A tile [128][64], then B tile [128][64]
    const int tn = blockIdx.x * 128;
    const int tm = blockIdx.y * 128;
    const int tid = threadIdx.x;
    const int wave = tid >> 6;
    const int lane = tid & 63;
    const int wm = (wave >> 1) * 64;
    const int wn = (wave & 1) * 64;
    const int laneR = lane & 15;
    const int laneK = (lane >> 4) * 8;

    f32x4 acc[4][4] = {};

    for (int k0 = 0; k0 < K; k0 += 64) {
        // stage 32KB: 8 issues/wave x 64 lanes x 16B
#pragma unroll
        for (int iss = 0; iss < 8; ++iss) {
            const int Lb = iss * 4096 + wave * 1024;   // wave-uniform LDS byte base
            const int off = Lb + lane * 16;
            const bf16* g;
            if (off < 16384) {                 // A region: row stride 128B (64 bf16)
                const int row = off >> 7;
                const int cb = off & 127;
                g = A + (size_t)(tm + row) * K + (k0 + (cb >> 1));
            } else {                           // B region
                const int o2 = off - 16384;
                const int row = o2 >> 7;
                const int cb = o2 & 127;
                g = W + (size_t)(tn + row) * K + (k0 + (cb >> 1));
            }
            gld_lds16(g, (bf16*)((char*)lds + Lb));
        }
        __syncthreads();

        const bf16* ldsA = lds;
        const bf16* ldsB = lds + 128 * 64;
#pragma unroll
        for (int ks = 0; ks < 2; ++ks) {
            bf16x8 af[4], bfr[4];
#pragma unroll
            for (int i = 0; i < 4; ++i) {
                af[i]  = *(const bf16x8*)(ldsA + (wm + i * 16 + laneR) * 64 + ks * 32 + laneK);
                bfr[i] = *(const bf16x8*)(ldsB + (wn + i * 16 + laneR) * 64 + ks * 32 + laneK);
            }
#pragma unroll
            for (int i = 0; i < 4; ++i)
#pragma unroll
                for (int j = 0; j < 4; ++j)
                    acc[i][j] = __builtin_amdgcn_mfma_f32_16x16x32_bf16(af[i], bfr[j], acc[i][j], 0, 0, 0);
        }
        __syncthreads();
    }

    // epilogue: C/D layout col=lane&15, row=(lane>>4)*4+r
    const int rbase = (lane >> 4) * 4;
#pragma unroll
    for (int i = 0; i < 4; ++i) {
#pragma unroll
        for (int j = 0; j < 4; ++j) {
#pragma unroll
            for (int r = 0; r < 4; ++r) {
                const size_t row = (size_t)tm + wm + i * 16 + rbase + r;
                const size_t col = (size_t)tn + wn + j * 16 + laneR;
                if (OUTF32) ((float*)Cout)[row * N + col] = acc[i][j][r];
                else        ((bf16*)Cout)[row * N + col] = (bf16)acc[i][j][r];
            }
        }
    }
}

// ---------------- RoPE on q (pre-scaled by log2e/sqrt(D)) and k; layout -> [h][s][d] ----------------
// C_qkv [2048][6144] bf16: cols 0..4095 q, 4096..5119 k, 5120..6143 v
// q is scaled by (1/sqrt(128)) * log2(e) so the flash kernel can use exp2.
__global__ void rope_qk_kernel(const bf16* __restrict__ C, bf16* __restrict__ Qr, bf16* __restrict__ Kr) {
    const int idx = blockIdx.x * 256 + threadIdx.x;
    const int NQ = 2048 * 32 * 64;
    const float QSC = 0.12751743561884394f;        // (1/sqrt(128)) * log2(e)
    const float LN1E4_64 = 0.14391156831212787f;   // ln(10000)/64
    if (idx < NQ) {
        const int f = idx & 63;
        const int t = idx >> 6;
        const int h = t & 31;
        const int s = t >> 5;
        const float x1 = (float)C[(size_t)s * 6144 + h * 128 + f];
        const float x2 = (float)C[(size_t)s * 6144 + h * 128 + f + 64];
        const float th = s * expf(-LN1E4_64 * (float)f);
        const float cs = cosf(th), sn = sinf(th);
        bf16* dst = Qr + ((size_t)h * 2048 + s) * 128 + f;
        dst[0]  = (bf16)((x1 * cs - x2 * sn) * QSC);
        dst[64] = (bf16)((x2 * cs + x1 * sn) * QSC);
    } else {
        const int i2 = idx - NQ;
        const int f = i2 & 63;
        const int t = i2 >> 6;
        const int h = t & 7;
        const int s = t >> 3;
        const float x1 = (float)C[(size_t)s * 6144 + 4096 + h * 128 + f];
        const float x2 = (float)C[(size_t)s * 6144 + 4096 + h * 128 + f + 64];
        const float th = s * expf(-LN1E4_64 * (float)f);
        const float cs = cosf(th), sn = sinf(th);
        bf16* dst = Kr + ((size_t)h * 2048 + s) * 128 + f;
        dst[0]  = (bf16)(x1 * cs - x2 * sn);
        dst[64] = (bf16)(x2 * cs + x1 * sn);
    }
}

// ---------------- V transpose: C_qkv v-cols -> Vt[hkv][d=128][s=2048] ----------------
__global__ void transpose_v_kernel(const bf16* __restrict__ C, bf16* __restrict__ Vt) {
    __shared__ __align__(16) unsigned short t[64][136];
    const int hkv = blockIdx.x >> 5;
    const int st = blockIdx.x & 31;
    const int s0 = st * 64;
    const int tid = threadIdx.x;
#pragma unroll
    for (int it = 0; it < 4; ++it) {
        const int l = it * 2048 + tid * 8;   // elem index in [64][128]
        const int r = l >> 7, c = l & 127;
        *(bf16x8*)&t[r][c] = *(const bf16x8*)&C[(size_t)(s0 + r) * 6144 + 5120 + hkv * 128 + c];
    }
    __syncthreads();
#pragma unroll
    for (int it = 0; it < 8; ++it) {
        const int o = it * 1024 + tid * 4;   // out elem index in [128 d][64 s]
        const int d = o >> 6, j = o & 63;
        ushort4 pk;
        pk.x = t[j + 0][d];
        pk.y = t[j + 1][d];
        pk.z = t[j + 2][d];
        pk.w = t[j + 3][d];
        *(ushort4*)&Vt[((size_t)hkv * 128 + d) * 2048 + s0 + j] = pk;
    }
}

// ---------------- causal GQA flash attention ----------------
// Block = 4 waves, each owns 32 q-rows. KVBLK=64.
// LDS 64KB total (=> 2 blocks/CU): K single-buffered 16KB, V dbuf 32KB, P 16KB.
// Per tile: QK(K[t]) -> sync -> stage K[t+1] (readers done) + V[t+1]->buf^1
//           -> softmax/P/PV(V[t]) -> sync (vmcnt0 drains stages).
// Softmax in log2 domain via native v_exp_f32 (__builtin_exp2f); defer-max (THR=8)
// skips the o-rescale when the running max doesn't grow.
__launch_bounds__(256, 2)
__global__ void flash_attn_kernel(const bf16* __restrict__ Qr, const bf16* __restrict__ Kr,
                                  const bf16* __restrict__ Vt, bf16* __restrict__ Aout) {
    __shared__ __align__(16) bf16 Klds[64 * 128];       // [kv][d], swizzled, 16KB single
    __shared__ __align__(16) bf16 Vlds[2][128 * 64];    // [d][kv], swizzled, 2x16KB
    __shared__ __align__(16) char Plds[4][4096];        // per-wave P [32][64] bf16, swizzled

    const int bid = blockIdx.x;
    const int hkv = bid & 7;
    const int r = bid >> 3;                 // 0..63
    const int h = hkv * 4 + (r & 3);
    const int qmi = r >> 2;                 // 0..15
    const int qb = (qmi < 8) ? (15 - qmi) : (qmi - 8);   // pair heavy with light per CU
    const int tid = threadIdx.x;
    const int wave = tid >> 6, lane = tid & 63;
    const int laneR = lane & 15;
    const int laneS = lane >> 4;
    const int laneK = laneS * 8;
    const int rbase = laneS * 4;
    const int q0w = qb * 128 + wave * 32;

    const bf16* Kh = Kr + (size_t)hkv * 2048 * 128;
    const bf16* Vh = Vt + (size_t)hkv * 128 * 2048;
    char* Pw = Plds[wave];

    auto stageK = [&](int t) {
        const int kv0 = t * 64;
#pragma unroll
        for (int s = 0; s < 4; ++s) {
            const int chunk = wave * 4 + s;
            const int L = chunk * 64 + lane;        // 16B-slot index
            const int krow = L >> 4, kc16 = L & 15; // 16 slots per 256B row
            gld_lds16(Kh + (size_t)(kv0 + krow) * 128 + ((kc16 ^ (krow & 7)) << 3),
                      &Klds[chunk * 512]);
        }
    };
    auto stageV = [&](int t, int buf) {
        const int kv0 = t * 64;
#pragma unroll
        for (int s = 0; s < 4; ++s) {
            const int chunk = wave * 4 + s;
            const int L = chunk * 64 + lane;
            const int vrow = L >> 3, vc8 = L & 7;   // 8 slots per 128B row
            gld_lds16(Vh + (size_t)vrow * 2048 + kv0 + ((vc8 ^ (vrow & 7)) << 3),
                      &Vlds[buf][chunk * 512]);
        }
    };

    // Q fragments (pre-scaled by log2e/sqrt(D))
    bf16x8 qf[2][4];
#pragma unroll
    for (int mi = 0; mi < 2; ++mi)
#pragma unroll
        for (int kc = 0; kc < 4; ++kc)
            qf[mi][kc] = *(const bf16x8*)&Qr[((size_t)h * 2048 + q0w + mi * 16 + laneR) * 128 + kc * 32 + laneK];

    f32x4 o[2][8] = {};
    float mrow[2][4], lrow[2][4];
#pragma unroll
    for (int mi = 0; mi < 2; ++mi)
#pragma unroll
        for (int rr = 0; rr < 4; ++rr) { mrow[mi][rr] = -1e30f; lrow[mi][rr] = 0.f; }

    const int ntiles = 2 * qb + 2;
    stageK(0);
    stageV(0, 0);
    __syncthreads();

    for (int t = 0; t < ntiles; ++t) {
        const int cur = t & 1;
        const int kv0 = t * 64;
        const bool live = (kv0 <= q0w + 31);

        f32x4 sc[2][4] = {};
        if (live) {
            // ---- scores = Q K^T (log2 domain) ----
            __builtin_amdgcn_s_setprio(1);
#pragma unroll
            for (int kc = 0; kc < 4; ++kc) {
                bf16x8 kf[4];
#pragma unroll
                for (int j = 0; j < 4; ++j) {
                    const int row = j * 16 + laneR;
                    kf[j] = *(const bf16x8*)((const char*)Klds + row * 256 +
                                             ((kc * 64 + laneS * 16) ^ ((row & 7) << 4)));
                }
#pragma unroll
                for (int mi = 0; mi < 2; ++mi)
#pragma unroll
                    for (int j = 0; j < 4; ++j)
                        sc[mi][j] = __builtin_amdgcn_mfma_f32_16x16x32_bf16(qf[mi][kc], kf[j], sc[mi][j], 0, 0, 0);
            }
            __builtin_amdgcn_s_setprio(0);
        }

        __syncthreads();   // all waves done reading Klds (reads consumed by MFMAs above)

        if (t + 1 < ntiles) {           // prefetch next tile; drained at end-of-tile sync
            stageK(t + 1);
            stageV(t + 1, cur ^ 1);
        }

        if (live) {
            if (kv0 + 63 > q0w) {   // diagonal region: causal mask
#pragma unroll
                for (int mi = 0; mi < 2; ++mi)
#pragma unroll
                    for (int j = 0; j < 4; ++j)
#pragma unroll
                        for (int rr = 0; rr < 4; ++rr) {
                            const int qr = q0w + mi * 16 + rbase + rr;
                            const int kr = kv0 + j * 16 + laneR;
                            if (kr > qr) sc[mi][j][rr] = -1e30f;
                        }
            }

            // ---- online softmax, defer-max: rescale only when max grows by >8 ----
#pragma unroll
            for (int mi = 0; mi < 2; ++mi) {
#pragma unroll
                for (int rr = 0; rr < 4; ++rr) {
                    float v = sc[mi][0][rr];
#pragma unroll
                    for (int j = 1; j < 4; ++j) v = fmaxf(v, sc[mi][j][rr]);
                    v = fmaxf(v, __shfl_xor(v, 1, 64));
                    v = fmaxf(v, __shfl_xor(v, 2, 64));
                    v = fmaxf(v, __shfl_xor(v, 4, 64));
                    v = fmaxf(v, __shfl_xor(v, 8, 64));
                    float m0 = mrow[mi][rr];
                    if (v - m0 > 8.0f) {                       // rescale path (rare after warmup)
                        const float fac = __builtin_exp2f(m0 - v);
                        mrow[mi][rr] = v;
                        m0 = v;
                        lrow[mi][rr] *= fac;
#pragma unroll
                        for (int j = 0; j < 8; ++j) o[mi][j][rr] *= fac;
                    }
                    float rs = 0.f;
#pragma unroll
                    for (int j = 0; j < 4; ++j) {
                        const float p = __builtin_exp2f(sc[mi][j][rr] - m0);   // bounded by 2^8
                        sc[mi][j][rr] = p;
                        rs += p;
                    }
                    rs += __shfl_xor(rs, 1, 64);
                    rs += __shfl_xor(rs, 2, 64);
                    rs += __shfl_xor(rs, 4, 64);
                    rs += __shfl_xor(rs, 8, 64);
                    lrow[mi][rr] += rs;
                }
            }

            // ---- write P into swizzled wave-private LDS ----
#pragma unroll
            for (int mi = 0; mi < 2; ++mi)
#pragma unroll
                for (int j = 0; j < 4; ++j)
#pragma unroll
                    for (int rr = 0; rr < 4; ++rr) {
                        const int row = mi * 16 + rbase + rr;
                        *(bf16*)(Pw + row * 128 + ((j * 32 + laneR * 2) ^ ((row & 7) << 4))) =
                            (bf16)sc[mi][j][rr];
                    }

            // ---- O += P V ----
            __builtin_amdgcn_s_setprio(1);
#pragma unroll
            for (int kc = 0; kc < 2; ++kc) {
                bf16x8 pf[2];
#pragma unroll
                for (int mi = 0; mi < 2; ++mi) {
                    const int row = mi * 16 + laneR;
                    pf[mi] = *(const bf16x8*)(Pw + row * 128 + ((kc * 64 + laneS * 16) ^ ((row & 7) << 4)));
                }
                bf16x8 vf[8];
#pragma unroll
                for (int j = 0; j < 8; ++j) {
                    const int row = j * 16 + laneR;
                    vf[j] = *(const bf16x8*)((const char*)Vlds[cur] + row * 128 +
                                             ((kc * 64 + laneS * 16) ^ ((row & 7) << 4)));
                }
#pragma unroll
                for (int mi = 0; mi < 2; ++mi)
#pragma unroll
                    for (int j = 0; j < 8; ++j)
                        o[mi][j] = __builtin_amdgcn_mfma_f32_16x16x32_bf16(pf[mi], vf[j], o[mi][j], 0, 0, 0);
            }
            __builtin_amdgcn_s_setprio(0);
        }

        __syncthreads();   // drains vmcnt(0): K[t+1]/V[t+1] complete; all waves done with V[cur]
    }

    // ---- normalize + write attn output [s][h*128+d] ----
#pragma unroll
    for (int mi = 0; mi < 2; ++mi) {
        float rinv[4];
#pragma unroll
        for (int rr = 0; rr < 4; ++rr) rinv[rr] = 1.0f / lrow[mi][rr];
#pragma unroll
        for (int j = 0; j < 8; ++j)
#pragma unroll
            for (int rr = 0; rr < 4; ++rr) {
                const size_t row = (size_t)q0w + mi * 16 + rbase + rr;
                Aout[row * 4096 + h * 128 + j * 16 + laneR] = (bf16)(o[mi][j][rr] * rinv[rr]);
            }
    }
}

// ---------------- launch ----------------
extern "C" void kernel_launch(void* const* d_in, const int* in_sizes, int n_in,
                              void* d_out, int out_size, void* d_ws, size_t ws_size,
                              hipStream_t stream) {
    const float* hidden = (const float*)d_in[0];
    const float* Wq = (const float*)d_in[1];
    const float* Wk = (const float*)d_in[2];
    const float* Wv = (const float*)d_in[3];
    const float* Wo = (const float*)d_in[4];
    float* out = (float*)d_out;
    char* ws = (char*)d_ws;

    // workspace layout (bytes):
    bf16* hs = (bf16*)(ws + 0);                 // [2048][4096]        16 MiB
    bf16* Wb = (bf16*)(ws + 16777216);          // [10240][4096]       80 MiB (Wq|Wk|Wv|Wo)
    bf16* Cq = (bf16*)(ws + 100663296);         // [2048][6144]        24 MiB
    bf16* Qr = (bf16*)(ws + 125829120);         // [32][2048][128]     16 MiB
    bf16* Kr = (bf16*)(ws + 142606336);         // [8][2048][128]       4 MiB
    bf16* Vt = (bf16*)(ws + 146800640);         // [8][128][2048]       4 MiB
    bf16* At = (bf16*)(ws + 150994944);         // [2048][4096]        16 MiB
    (void)ws_size; (void)in_sizes; (void)n_in; (void)out_size;

    // 1. casts
    cvt4_kernel<<<8192, 256, 0, stream>>>((const float4*)hidden, (ushort4*)hs, 2097152);
    cvt4_kernel<<<16384, 256, 0, stream>>>((const float4*)Wq, (ushort4*)(Wb + 0), 4194304);
    cvt4_kernel<<<4096, 256, 0, stream>>>((const float4*)Wk, (ushort4*)(Wb + 16777216), 1048576);
    cvt4_kernel<<<4096, 256, 0, stream>>>((const float4*)Wv, (ushort4*)(Wb + 20971520), 1048576);
    cvt4_kernel<<<16384, 256, 0, stream>>>((const float4*)Wo, (ushort4*)(Wb + 25165824), 4194304);

    // 2. fused QKV projection: [2048,6144] = hs @ Wqkv^T
    gemm_bt_kernel<false><<<dim3(48, 16), 256, 0, stream>>>(hs, Wb, Cq, 2048, 6144, 4096);

    // 3. RoPE (+transpose to [h][s][d]); q pre-scaled by log2e/sqrt(D)
    rope_qk_kernel<<<20480, 256, 0, stream>>>(Cq, Qr, Kr);

    // 4. V transpose -> [hkv][d][s]
    transpose_v_kernel<<<256, 256, 0, stream>>>(Cq, Vt);

    // 5. causal GQA flash attention -> At [2048][4096] bf16
    flash_attn_kernel<<<512, 256, 0, stream>>>(Qr, Kr, Vt, At);

    // 6. output projection: out = At @ Wo^T (fp32 out)
    gemm_bt_kernel<true><<<dim3(32, 16), 256, 0, stream>>>(At, Wb + 25165824, out, 2048, 4096, 4096);
}

// Round 6
// 389.960 us; speedup vs baseline: 1.5139x; 1.0660x over previous
//
#include <hip/hip_runtime.h>

#define AS1 __attribute__((address_space(1)))
#define AS3 __attribute__((address_space(3)))

typedef __bf16 bf16;
typedef __bf16 bf16x8 __attribute__((ext_vector_type(8)));
typedef float f32x4 __attribute__((ext_vector_type(4)));

__device__ __forceinline__ void gld_lds16(const bf16* g, bf16* l) {
    __builtin_amdgcn_global_load_lds((const AS1 void*)g, (AS3 void*)l, 16, 0, 0);
}

// ---------------- fp32 -> bf16 cast ----------------
__global__ void cvt4_kernel(const float4* __restrict__ in, ushort4* __restrict__ out, int n4) {
    const int i = blockIdx.x * 256 + threadIdx.x;
    if (i >= n4) return;
    const float4 v = in[i];
    ushort4 r;
    r.x = __builtin_bit_cast(unsigned short, (bf16)v.x);
    r.y = __builtin_bit_cast(unsigned short, (bf16)v.y);
    r.z = __builtin_bit_cast(unsigned short, (bf16)v.z);
    r.w = __builtin_bit_cast(unsigned short, (bf16)v.w);
    out[i] = r;
}

// ---------------- GEMM: C[M,N] = A[M,K] * W[N,K]^T (both row-major, K contiguous) ----------------
// 128x128 tile, BK=64, 256 threads (4 waves in 2x2), mfma 16x16x32 bf16.  (unchanged from R5)
template <bool OUTF32>
__global__ void gemm_bt_kernel(const bf16* __restrict__ A, const bf16* __restrict__ W,
                               void* __restrict__ Cout, int M, int N, int K) {
    __shared__ __align__(16) bf16 lds[2 * 128 * 64];   // A tile [128][64], then B tile [128][64]
    const int tn = blockIdx.x * 128;
    const int tm = blockIdx.y * 128;
    const int tid = threadIdx.x;
    const int wave = tid >> 6;
    const int lane = tid & 63;
    const int wm = (wave >> 1) * 64;
    const int wn = (wave & 1) * 64;
    const int laneR = lane & 15;
    const int laneK = (lane >> 4) * 8;

    f32x4 acc[4][4] = {};

    for (int k0 = 0; k0 < K; k0 += 64) {
#pragma unroll
        for (int iss = 0; iss < 8; ++iss) {
            const int Lb = iss * 4096 + wave * 1024;   // wave-uniform LDS byte base
            const int off = Lb + lane * 16;
            const bf16* g;
            if (off < 16384) {                 // A region
                const int row = off >> 7;
                const int cb = off & 127;
                g = A + (size_t)(tm + row) * K + (k0 + (cb >> 1));
            } else {                           // B region
                const int o2 = off - 16384;
                const int row = o2 >> 7;
                const int cb = o2 & 127;
                g = W + (size_t)(tn + row) * K + (k0 + (cb >> 1));
            }
            gld_lds16(g, (bf16*)((char*)lds + Lb));
        }
        __syncthreads();

        const bf16* ldsA = lds;
        const bf16* ldsB = lds + 128 * 64;
#pragma unroll
        for (int ks = 0; ks < 2; ++ks) {
            bf16x8 af[4], bfr[4];
#pragma unroll
            for (int i = 0; i < 4; ++i) {
                af[i]  = *(const bf16x8*)(ldsA + (wm + i * 16 + laneR) * 64 + ks * 32 + laneK);
                bfr[i] = *(const bf16x8*)(ldsB + (wn + i * 16 + laneR) * 64 + ks * 32 + laneK);
            }
#pragma unroll
            for (int i = 0; i < 4; ++i)
#pragma unroll
                for (int j = 0; j < 4; ++j)
                    acc[i][j] = __builtin_amdgcn_mfma_f32_16x16x32_bf16(af[i], bfr[j], acc[i][j], 0, 0, 0);
        }
        __syncthreads();
    }

    const int rbase = (lane >> 4) * 4;
#pragma unroll
    for (int i = 0; i < 4; ++i) {
#pragma unroll
        for (int j = 0; j < 4; ++j) {
#pragma unroll
            for (int r = 0; r < 4; ++r) {
                const size_t row = (size_t)tm + wm + i * 16 + rbase + r;
                const size_t col = (size_t)tn + wn + j * 16 + laneR;
                if (OUTF32) ((float*)Cout)[row * N + col] = acc[i][j][r];
                else        ((bf16*)Cout)[row * N + col] = (bf16)acc[i][j][r];
            }
        }
    }
}

// ---------------- RoPE on q (pre-scaled by log2e/sqrt(D)) and k; layout -> [h][s][d] ----------------
__global__ void rope_qk_kernel(const bf16* __restrict__ C, bf16* __restrict__ Qr, bf16* __restrict__ Kr) {
    const int idx = blockIdx.x * 256 + threadIdx.x;
    const int NQ = 2048 * 32 * 64;
    const float QSC = 0.12751743561884394f;        // (1/sqrt(128)) * log2(e)
    const float LN1E4_64 = 0.14391156831212787f;   // ln(10000)/64
    if (idx < NQ) {
        const int f = idx & 63;
        const int t = idx >> 6;
        const int h = t & 31;
        const int s = t >> 5;
        const float x1 = (float)C[(size_t)s * 6144 + h * 128 + f];
        const float x2 = (float)C[(size_t)s * 6144 + h * 128 + f + 64];
        const float th = s * expf(-LN1E4_64 * (float)f);
        const float cs = cosf(th), sn = sinf(th);
        bf16* dst = Qr + ((size_t)h * 2048 + s) * 128 + f;
        dst[0]  = (bf16)((x1 * cs - x2 * sn) * QSC);
        dst[64] = (bf16)((x2 * cs + x1 * sn) * QSC);
    } else {
        const int i2 = idx - NQ;
        const int f = i2 & 63;
        const int t = i2 >> 6;
        const int h = t & 7;
        const int s = t >> 3;
        const float x1 = (float)C[(size_t)s * 6144 + 4096 + h * 128 + f];
        const float x2 = (float)C[(size_t)s * 6144 + 4096 + h * 128 + f + 64];
        const float th = s * expf(-LN1E4_64 * (float)f);
        const float cs = cosf(th), sn = sinf(th);
        bf16* dst = Kr + ((size_t)h * 2048 + s) * 128 + f;
        dst[0]  = (bf16)(x1 * cs - x2 * sn);
        dst[64] = (bf16)(x2 * cs + x1 * sn);
    }
}

// ---------------- V transpose: C_qkv v-cols -> Vt[hkv][d=128][s=2048] ----------------
__global__ void transpose_v_kernel(const bf16* __restrict__ C, bf16* __restrict__ Vt) {
    __shared__ __align__(16) unsigned short t[64][136];
    const int hkv = blockIdx.x >> 5;
    const int st = blockIdx.x & 31;
    const int s0 = st * 64;
    const int tid = threadIdx.x;
#pragma unroll
    for (int it = 0; it < 4; ++it) {
        const int l = it * 2048 + tid * 8;
        const int r = l >> 7, c = l & 127;
        *(bf16x8*)&t[r][c] = *(const bf16x8*)&C[(size_t)(s0 + r) * 6144 + 5120 + hkv * 128 + c];
    }
    __syncthreads();
#pragma unroll
    for (int it = 0; it < 8; ++it) {
        const int o = it * 1024 + tid * 4;
        const int d = o >> 6, j = o & 63;
        ushort4 pk;
        pk.x = t[j + 0][d];
        pk.y = t[j + 1][d];
        pk.z = t[j + 2][d];
        pk.w = t[j + 3][d];
        *(ushort4*)&Vt[((size_t)hkv * 128 + d) * 2048 + s0 + j] = pk;
    }
}

// ---------------- causal GQA flash attention, equal-work persistent blocks ----------------
// Grid = 256 (1 block/CU). Block = 4 waves x 32 q-rows = one 128-row q-block; each block
// sequentially processes the PAIR (qb=15-a, qb=a) => exactly 17 KV-tiles (KVBLK=128) per
// block, perfectly balanced. K and V double-buffered (LDS 64+64+16=144KB); ONE barrier
// per tile: stage(t+1 -> buf^1) issued at tile start, whole tile of compute hides the
// latency, end-of-tile __syncthreads drains vmcnt. Swizzles as verified in R4/R5
// (pre-swizzled global source + XOR on LDS reads). Softmax: log2-domain native exp2,
// defer-max (THR=8). P written per-wave in two 64-kv halves (buffer reused, no barrier).
__launch_bounds__(256, 1)
__global__ void flash_attn_kernel(const bf16* __restrict__ Qr, const bf16* __restrict__ Kr,
                                  const bf16* __restrict__ Vt, bf16* __restrict__ Aout) {
    __shared__ __align__(16) bf16 Klds[2][128 * 128];   // [kv][d], swizzled, 2x32KB
    __shared__ __align__(16) bf16 Vlds[2][128 * 128];   // [d][kv], swizzled, 2x32KB
    __shared__ __align__(16) char Plds[4][4096];        // per-wave P [32][64] bf16, swizzled

    const int bid = blockIdx.x;
    const int hkv = bid & 7;                 // XCD L2 affinity
    const int r = bid >> 3;                  // 0..31
    const int h = hkv * 4 + (r & 3);
    const int pa = r >> 2;                   // 0..7
    const int qbA = 15 - pa, qbB = pa;       // heavy pass, then light pass (17 tiles total)
    const int tid = threadIdx.x;
    const int wave = tid >> 6, lane = tid & 63;
    const int laneR = lane & 15;
    const int laneS = lane >> 4;
    const int laneK = laneS * 8;
    const int rbase = laneS * 4;

    const bf16* Kh = Kr + (size_t)hkv * 2048 * 128;
    const bf16* Vh = Vt + (size_t)hkv * 128 * 2048;
    char* Pw = Plds[wave];

    // stage a 128-kv tile (32KB each for K and V); 8 issues/wave each; 16B granules
    auto stageK = [&](int kv0, int buf) {
#pragma unroll
        for (int s = 0; s < 8; ++s) {
            const int chunk = wave * 8 + s;          // 0..31
            const int L = chunk * 64 + lane;         // 16B-slot index, 0..2047
            const int row = L >> 4, sl = L & 15;     // 16 slots per 256B row
            gld_lds16(Kh + (size_t)(kv0 + row) * 128 + ((sl ^ (row & 7)) << 3),
                      &Klds[buf][chunk * 512]);
        }
    };
    auto stageV = [&](int kv0, int buf) {
#pragma unroll
        for (int s = 0; s < 8; ++s) {
            const int chunk = wave * 8 + s;
            const int L = chunk * 64 + lane;
            const int row = L >> 4, sl = L & 15;     // row = d, 16 slots per 256B row
            gld_lds16(Vh + (size_t)row * 2048 + kv0 + ((sl ^ (row & 7)) << 3),
                      &Vlds[buf][chunk * 512]);
        }
    };

    // per-pass state
    int qbcur = qbA;
    int q0w = qbA * 128 + wave * 32;
    int tloc = 0;

    // Q fragments for current pass (pre-scaled by log2e/sqrt(D))
    bf16x8 qf[2][4];
    auto loadQ = [&]() {
#pragma unroll
        for (int mi = 0; mi < 2; ++mi)
#pragma unroll
            for (int kc = 0; kc < 4; ++kc)
                qf[mi][kc] = *(const bf16x8*)&Qr[((size_t)h * 2048 + q0w + mi * 16 + laneR) * 128 + kc * 32 + laneK];
    };
    loadQ();

    f32x4 o[2][8] = {};
    float mrow[2][4], lrow[2][4];
#pragma unroll
    for (int mi = 0; mi < 2; ++mi)
#pragma unroll
        for (int rr = 0; rr < 4; ++rr) { mrow[mi][rr] = -1e30f; lrow[mi][rr] = 0.f; }

    stageK(0, 0);
    stageV(0, 0);
    __syncthreads();

    for (int g = 0; g < 17; ++g) {
        const int buf = g & 1;
        if (g < 16) {                         // prefetch tile g+1 into buf^1
            const int tn = (g + 1 <= qbA) ? (g + 1) : (g - qbA);
            stageK(tn * 128, buf ^ 1);
            stageV(tn * 128, buf ^ 1);
        }
        const int kv0 = tloc * 128;

        // ---- scores = Q K^T (log2 domain) ----
        f32x4 sc[2][8] = {};
        __builtin_amdgcn_s_setprio(1);
#pragma unroll
        for (int kc = 0; kc < 4; ++kc) {
            bf16x8 kf[8];
#pragma unroll
            for (int j = 0; j < 8; ++j) {
                const int row = j * 16 + laneR;
                kf[j] = *(const bf16x8*)((const char*)Klds[buf] + row * 256 +
                                         ((kc * 64 + laneS * 16) ^ ((row & 7) << 4)));
            }
#pragma unroll
            for (int mi = 0; mi < 2; ++mi)
#pragma unroll
                for (int j = 0; j < 8; ++j)
                    sc[mi][j] = __builtin_amdgcn_mfma_f32_16x16x32_bf16(qf[mi][kc], kf[j], sc[mi][j], 0, 0, 0);
        }
        __builtin_amdgcn_s_setprio(0);

        if (tloc == qbcur) {                  // diagonal tile: causal mask
#pragma unroll
            for (int mi = 0; mi < 2; ++mi)
#pragma unroll
                for (int j = 0; j < 8; ++j)
#pragma unroll
                    for (int rr = 0; rr < 4; ++rr) {
                        const int qr = q0w + mi * 16 + rbase + rr;
                        const int kr = kv0 + j * 16 + laneR;
                        if (kr > qr) sc[mi][j][rr] = -1e30f;
                    }
        }

        // ---- online softmax, defer-max (rescale only when max grows by >8) ----
#pragma unroll
        for (int mi = 0; mi < 2; ++mi) {
#pragma unroll
            for (int rr = 0; rr < 4; ++rr) {
                float v = sc[mi][0][rr];
#pragma unroll
                for (int j = 1; j < 8; ++j) v = fmaxf(v, sc[mi][j][rr]);
                v = fmaxf(v, __shfl_xor(v, 1, 64));
                v = fmaxf(v, __shfl_xor(v, 2, 64));
                v = fmaxf(v, __shfl_xor(v, 4, 64));
                v = fmaxf(v, __shfl_xor(v, 8, 64));
                float m0 = mrow[mi][rr];
                if (v - m0 > 8.0f) {
                    const float fac = __builtin_exp2f(m0 - v);
                    mrow[mi][rr] = v;
                    m0 = v;
                    lrow[mi][rr] *= fac;
#pragma unroll
                    for (int j = 0; j < 8; ++j) o[mi][j][rr] *= fac;
                }
                float rs = 0.f;
#pragma unroll
                for (int j = 0; j < 8; ++j) {
                    const float p = __builtin_exp2f(sc[mi][j][rr] - m0);
                    sc[mi][j][rr] = p;
                    rs += p;
                }
                rs += __shfl_xor(rs, 1, 64);
                rs += __shfl_xor(rs, 2, 64);
                rs += __shfl_xor(rs, 4, 64);
                rs += __shfl_xor(rs, 8, 64);
                lrow[mi][rr] += rs;
            }
        }

        // ---- P -> LDS and O += P V, in two 64-kv halves (wave-private buffer) ----
#pragma unroll
        for (int hf = 0; hf < 2; ++hf) {
#pragma unroll
            for (int mi = 0; mi < 2; ++mi)
#pragma unroll
                for (int j = 0; j < 4; ++j)
#pragma unroll
                    for (int rr = 0; rr < 4; ++rr) {
                        const int row = mi * 16 + rbase + rr;
                        *(bf16*)(Pw + row * 128 + ((j * 32 + laneR * 2) ^ ((row & 7) << 4))) =
                            (bf16)sc[mi][hf * 4 + j][rr];
                    }
            __builtin_amdgcn_s_setprio(1);
#pragma unroll
            for (int kc = 0; kc < 2; ++kc) {
                bf16x8 pf[2];
#pragma unroll
                for (int mi = 0; mi < 2; ++mi) {
                    const int row = mi * 16 + laneR;
                    pf[mi] = *(const bf16x8*)(Pw + row * 128 + ((kc * 64 + laneS * 16) ^ ((row & 7) << 4)));
                }
                const int kcg = hf * 2 + kc;          // global kv-chunk 0..3
                bf16x8 vf[8];
#pragma unroll
                for (int j = 0; j < 8; ++j) {
                    const int row = j * 16 + laneR;   // d-row
                    vf[j] = *(const bf16x8*)((const char*)Vlds[buf] + row * 256 +
                                             ((kcg * 64 + laneS * 16) ^ ((row & 7) << 4)));
                }
#pragma unroll
                for (int mi = 0; mi < 2; ++mi)
#pragma unroll
                    for (int j = 0; j < 8; ++j)
                        o[mi][j] = __builtin_amdgcn_mfma_f32_16x16x32_bf16(pf[mi], vf[j], o[mi][j], 0, 0, 0);
            }
            __builtin_amdgcn_s_setprio(0);
        }

        // ---- pass boundary: write out, reset state, switch to light q-block ----
        if (tloc == qbcur) {
#pragma unroll
            for (int mi = 0; mi < 2; ++mi) {
                float rinv[4];
#pragma unroll
                for (int rr = 0; rr < 4; ++rr) rinv[rr] = 1.0f / lrow[mi][rr];
#pragma unroll
                for (int j = 0; j < 8; ++j)
#pragma unroll
                    for (int rr = 0; rr < 4; ++rr) {
                        const size_t row = (size_t)q0w + mi * 16 + rbase + rr;
                        Aout[row * 4096 + h * 128 + j * 16 + laneR] = (bf16)(o[mi][j][rr] * rinv[rr]);
                    }
            }
            if (g < 16) {
                qbcur = qbB;
                q0w = qbB * 128 + wave * 32;
                tloc = 0;
                loadQ();
#pragma unroll
                for (int mi = 0; mi < 2; ++mi)
#pragma unroll
                    for (int rr = 0; rr < 4; ++rr) { mrow[mi][rr] = -1e30f; lrow[mi][rr] = 0.f; }
#pragma unroll
                for (int mi = 0; mi < 2; ++mi)
#pragma unroll
                    for (int j = 0; j < 8; ++j)
                        o[mi][j] = f32x4{0.f, 0.f, 0.f, 0.f};
            }
        } else {
            ++tloc;
        }

        __syncthreads();   // drains vmcnt (tile g+1 staged) + all waves done with buf
    }
}

// ---------------- launch ----------------
extern "C" void kernel_launch(void* const* d_in, const int* in_sizes, int n_in,
                              void* d_out, int out_size, void* d_ws, size_t ws_size,
                              hipStream_t stream) {
    const float* hidden = (const float*)d_in[0];
    const float* Wq = (const float*)d_in[1];
    const float* Wk = (const float*)d_in[2];
    const float* Wv = (const float*)d_in[3];
    const float* Wo = (const float*)d_in[4];
    float* out = (float*)d_out;
    char* ws = (char*)d_ws;

    // workspace layout (bytes):
    bf16* hs = (bf16*)(ws + 0);                 // [2048][4096]        16 MiB
    bf16* Wb = (bf16*)(ws + 16777216);          // [10240][4096]       80 MiB (Wq|Wk|Wv|Wo)
    bf16* Cq = (bf16*)(ws + 100663296);         // [2048][6144]        24 MiB
    bf16* Qr = (bf16*)(ws + 125829120);         // [32][2048][128]     16 MiB
    bf16* Kr = (bf16*)(ws + 142606336);         // [8][2048][128]       4 MiB
    bf16* Vt = (bf16*)(ws + 146800640);         // [8][128][2048]       4 MiB
    bf16* At = (bf16*)(ws + 150994944);         // [2048][4096]        16 MiB
    (void)ws_size; (void)in_sizes; (void)n_in; (void)out_size;

    // 1. casts
    cvt4_kernel<<<8192, 256, 0, stream>>>((const float4*)hidden, (ushort4*)hs, 2097152);
    cvt4_kernel<<<16384, 256, 0, stream>>>((const float4*)Wq, (ushort4*)(Wb + 0), 4194304);
    cvt4_kernel<<<4096, 256, 0, stream>>>((const float4*)Wk, (ushort4*)(Wb + 16777216), 1048576);
    cvt4_kernel<<<4096, 256, 0, stream>>>((const float4*)Wv, (ushort4*)(Wb + 20971520), 1048576);
    cvt4_kernel<<<16384, 256, 0, stream>>>((const float4*)Wo, (ushort4*)(Wb + 25165824), 4194304);

    // 2. fused QKV projection: [2048,6144] = hs @ Wqkv^T
    gemm_bt_kernel<false><<<dim3(48, 16), 256, 0, stream>>>(hs, Wb, Cq, 2048, 6144, 4096);

    // 3. RoPE (+transpose to [h][s][d]); q pre-scaled by log2e/sqrt(D)
    rope_qk_kernel<<<20480, 256, 0, stream>>>(Cq, Qr, Kr);

    // 4. V transpose -> [hkv][d][s]
    transpose_v_kernel<<<256, 256, 0, stream>>>(Cq, Vt);

    // 5. causal GQA flash attention -> At [2048][4096] bf16 (256 equal-work blocks)
    flash_attn_kernel<<<256, 256, 0, stream>>>(Qr, Kr, Vt, At);

    // 6. output projection: out = At @ Wo^T (fp32 out)
    gemm_bt_kernel<true><<<dim3(32, 16), 256, 0, stream>>>(At, Wb + 25165824, out, 2048, 4096, 4096);
}

// Round 7
// 353.045 us; speedup vs baseline: 1.6722x; 1.1046x over previous
//
#include <hip/hip_runtime.h>

#define AS1 __attribute__((address_space(1)))
#define AS3 __attribute__((address_space(3)))

typedef __bf16 bf16;
typedef __bf16 bf16x8 __attribute__((ext_vector_type(8)));
typedef float f32x4 __attribute__((ext_vector_type(4)));

__device__ __forceinline__ void gld_lds16(const bf16* g, bf16* l) {
    __builtin_amdgcn_global_load_lds((const AS1 void*)g, (AS3 void*)l, 16, 0, 0);
}

// ---------------- fp32 -> bf16 cast ----------------
__global__ void cvt4_kernel(const float4* __restrict__ in, ushort4* __restrict__ out, int n4) {
    const int i = blockIdx.x * 256 + threadIdx.x;
    if (i >= n4) return;
    const float4 v = in[i];
    ushort4 r;
    r.x = __builtin_bit_cast(unsigned short, (bf16)v.x);
    r.y = __builtin_bit_cast(unsigned short, (bf16)v.y);
    r.z = __builtin_bit_cast(unsigned short, (bf16)v.z);
    r.w = __builtin_bit_cast(unsigned short, (bf16)v.w);
    out[i] = r;
}

// ---------------- GEMM, counted-vmcnt ring pipeline ----------------
// C[M,N] = A[M,K] * W[N,K]^T, both row-major K-contiguous, mfma 16x16x32 bf16.
// Tile 128 x BN, BK=32, 512 threads (8 waves, 2M x 4N), per-wave 64 x BN/4.
// LDS: ring of 4 K-tile slots (A[128][32] + B[BN][32] each). Tile t computed from
// slot t&3 while tile t+3 is STAGED into slot (t+3)&3 == (t-1)&3 -- that slot's
// readers all finished before tile t-1's end barrier, so early-landing gld_lds
// writes cannot race reads. Per tile: raw s_barrier + literal s_waitcnt vmcnt(2I)
// (I = per-thread stage issues; never drains to 0 in steady state). 64B LDS rows
// + b128 frag reads are bank-uniform (8 lanes per 4-bank slot) -- no swizzle needed.
template <int BN, bool OUTF32>
__launch_bounds__(512, 2)
__global__ void gemm8p_kernel(const bf16* __restrict__ A, const bf16* __restrict__ W,
                              void* __restrict__ Cout, int M, int N, int K) {
    constexpr int NF = BN / 64;        // N-frags per wave: 6 (BN=384) or 4 (BN=256)
    constexpr int IB = BN / 128;       // B stage issues per thread: 3 or 2
    __shared__ __align__(16) bf16 Asl[4][128 * 32];
    __shared__ __align__(16) bf16 Bsl[4][BN * 32];

    const int tn = blockIdx.x * BN;
    const int tm = blockIdx.y * 128;
    const int tid = threadIdx.x;
    const int wave = tid >> 6;
    const int lane = tid & 63;
    const int laneR = lane & 15;
    const int laneS = lane >> 4;
    const int wmB = (wave >> 2) * 64;          // wave M offset within 128
    const int wnB = (wave & 3) * (BN / 4);     // wave N offset within BN
    const int NT = K >> 5;                     // K-tiles of 32

    auto stage = [&](int t) {
        const int slot = t & 3;
        const int k0 = t << 5;
        {
            const int row = tid >> 2, g = tid & 3;
            gld_lds16(A + (size_t)(tm + row) * K + k0 + g * 8, &Asl[slot][wave * 512]);
        }
#pragma unroll
        for (int i = 0; i < IB; ++i) {
            const int row = i * 128 + (tid >> 2), g = tid & 3;
            gld_lds16(W + (size_t)(tn + row) * K + k0 + g * 8,
                      &Bsl[slot][i * 4096 + wave * 512]);
        }
    };

    f32x4 acc[4][NF] = {};

    // prologue: stage tiles 0,1,2; wait own issues <= 2I (tile 0 landed); barrier
    stage(0); stage(1); stage(2);
    if constexpr (BN == 384) asm volatile("s_waitcnt vmcnt(8)" ::: "memory");
    else                     asm volatile("s_waitcnt vmcnt(6)" ::: "memory");
    __builtin_amdgcn_sched_barrier(0);
    __builtin_amdgcn_s_barrier();
    __builtin_amdgcn_sched_barrier(0);

    for (int t = 0; t < NT; ++t) {
        const int slot = t & 3;
        bf16x8 af[4], bfr[NF];
#pragma unroll
        for (int mf = 0; mf < 4; ++mf)
            af[mf] = *(const bf16x8*)&Asl[slot][(wmB + mf * 16 + laneR) * 32 + laneS * 8];
#pragma unroll
        for (int nf = 0; nf < NF; ++nf)
            bfr[nf] = *(const bf16x8*)&Bsl[slot][(wnB + nf * 16 + laneR) * 32 + laneS * 8];

        if (t + 3 < NT) stage(t + 3);   // into slot (t-1)&3: readers done at tile t-1's barrier

#pragma unroll
        for (int mf = 0; mf < 4; ++mf)
#pragma unroll
            for (int nf = 0; nf < NF; ++nf)
                acc[mf][nf] = __builtin_amdgcn_mfma_f32_16x16x32_bf16(af[mf], bfr[nf], acc[mf][nf], 0, 0, 0);

        __builtin_amdgcn_sched_barrier(0);
        // end-of-tile: ensure tile t+1 resident before any wave reads it next iter
        if (t + 3 < NT) {               // tiles t+2,t+3 may stay in flight
            if constexpr (BN == 384) asm volatile("s_waitcnt vmcnt(8)" ::: "memory");
            else                     asm volatile("s_waitcnt vmcnt(6)" ::: "memory");
        } else if (t + 3 == NT) {       // only t+2 may stay in flight
            if constexpr (BN == 384) asm volatile("s_waitcnt vmcnt(4)" ::: "memory");
            else                     asm volatile("s_waitcnt vmcnt(3)" ::: "memory");
        } else {
            asm volatile("s_waitcnt vmcnt(0)" ::: "memory");
        }
        __builtin_amdgcn_sched_barrier(0);
        __builtin_amdgcn_s_barrier();
        __builtin_amdgcn_sched_barrier(0);
    }

    // epilogue: C/D layout col=lane&15, row=(lane>>4)*4+rr
    const int rbase = laneS * 4;
#pragma unroll
    for (int mf = 0; mf < 4; ++mf)
#pragma unroll
        for (int nf = 0; nf < NF; ++nf)
#pragma unroll
            for (int rr = 0; rr < 4; ++rr) {
                const size_t row = (size_t)tm + wmB + mf * 16 + rbase + rr;
                const size_t col = (size_t)tn + wnB + nf * 16 + laneR;
                if constexpr (OUTF32) ((float*)Cout)[row * N + col] = acc[mf][nf][rr];
                else                  ((bf16*)Cout)[row * N + col] = (bf16)acc[mf][nf][rr];
            }
    (void)M;
}

// ---------------- RoPE on q (pre-scaled by log2e/sqrt(D)) and k; layout -> [h][s][d] ----------------
__global__ void rope_qk_kernel(const bf16* __restrict__ C, bf16* __restrict__ Qr, bf16* __restrict__ Kr) {
    const int idx = blockIdx.x * 256 + threadIdx.x;
    const int NQ = 2048 * 32 * 64;
    const float QSC = 0.12751743561884394f;        // (1/sqrt(128)) * log2(e)
    const float LN1E4_64 = 0.14391156831212787f;   // ln(10000)/64
    if (idx < NQ) {
        const int f = idx & 63;
        const int t = idx >> 6;
        const int h = t & 31;
        const int s = t >> 5;
        const float x1 = (float)C[(size_t)s * 6144 + h * 128 + f];
        const float x2 = (float)C[(size_t)s * 6144 + h * 128 + f + 64];
        const float th = s * expf(-LN1E4_64 * (float)f);
        const float cs = cosf(th), sn = sinf(th);
        bf16* dst = Qr + ((size_t)h * 2048 + s) * 128 + f;
        dst[0]  = (bf16)((x1 * cs - x2 * sn) * QSC);
        dst[64] = (bf16)((x2 * cs + x1 * sn) * QSC);
    } else {
        const int i2 = idx - NQ;
        const int f = i2 & 63;
        const int t = i2 >> 6;
        const int h = t & 7;
        const int s = t >> 3;
        const float x1 = (float)C[(size_t)s * 6144 + 4096 + h * 128 + f];
        const float x2 = (float)C[(size_t)s * 6144 + 4096 + h * 128 + f + 64];
        const float th = s * expf(-LN1E4_64 * (float)f);
        const float cs = cosf(th), sn = sinf(th);
        bf16* dst = Kr + ((size_t)h * 2048 + s) * 128 + f;
        dst[0]  = (bf16)(x1 * cs - x2 * sn);
        dst[64] = (bf16)(x2 * cs + x1 * sn);
    }
}

// ---------------- V transpose: C_qkv v-cols -> Vt[hkv][d=128][s=2048] ----------------
__global__ void transpose_v_kernel(const bf16* __restrict__ C, bf16* __restrict__ Vt) {
    __shared__ __align__(16) unsigned short t[64][136];
    const int hkv = blockIdx.x >> 5;
    const int st = blockIdx.x & 31;
    const int s0 = st * 64;
    const int tid = threadIdx.x;
#pragma unroll
    for (int it = 0; it < 4; ++it) {
        const int l = it * 2048 + tid * 8;
        const int r = l >> 7, c = l & 127;
        *(bf16x8*)&t[r][c] = *(const bf16x8*)&C[(size_t)(s0 + r) * 6144 + 5120 + hkv * 128 + c];
    }
    __syncthreads();
#pragma unroll
    for (int it = 0; it < 8; ++it) {
        const int o = it * 1024 + tid * 4;
        const int d = o >> 6, j = o & 63;
        ushort4 pk;
        pk.x = t[j + 0][d];
        pk.y = t[j + 1][d];
        pk.z = t[j + 2][d];
        pk.w = t[j + 3][d];
        *(ushort4*)&Vt[((size_t)hkv * 128 + d) * 2048 + s0 + j] = pk;
    }
}

// ---------------- causal GQA flash attention, equal-work persistent blocks (R6) ----------------
__launch_bounds__(256, 1)
__global__ void flash_attn_kernel(const bf16* __restrict__ Qr, const bf16* __restrict__ Kr,
                                  const bf16* __restrict__ Vt, bf16* __restrict__ Aout) {
    __shared__ __align__(16) bf16 Klds[2][128 * 128];   // [kv][d], swizzled, 2x32KB
    __shared__ __align__(16) bf16 Vlds[2][128 * 128];   // [d][kv], swizzled, 2x32KB
    __shared__ __align__(16) char Plds[4][4096];        // per-wave P [32][64] bf16, swizzled

    const int bid = blockIdx.x;
    const int hkv = bid & 7;                 // XCD L2 affinity
    const int r = bid >> 3;                  // 0..31
    const int h = hkv * 4 + (r & 3);
    const int pa = r >> 2;                   // 0..7
    const int qbA = 15 - pa, qbB = pa;       // heavy pass, then light pass (17 tiles total)
    const int tid = threadIdx.x;
    const int wave = tid >> 6, lane = tid & 63;
    const int laneR = lane & 15;
    const int laneS = lane >> 4;
    const int laneK = laneS * 8;
    const int rbase = laneS * 4;

    const bf16* Kh = Kr + (size_t)hkv * 2048 * 128;
    const bf16* Vh = Vt + (size_t)hkv * 128 * 2048;
    char* Pw = Plds[wave];

    auto stageK = [&](int kv0, int buf) {
#pragma unroll
        for (int s = 0; s < 8; ++s) {
            const int chunk = wave * 8 + s;
            const int L = chunk * 64 + lane;
            const int row = L >> 4, sl = L & 15;
            gld_lds16(Kh + (size_t)(kv0 + row) * 128 + ((sl ^ (row & 7)) << 3),
                      &Klds[buf][chunk * 512]);
        }
    };
    auto stageV = [&](int kv0, int buf) {
#pragma unroll
        for (int s = 0; s < 8; ++s) {
            const int chunk = wave * 8 + s;
            const int L = chunk * 64 + lane;
            const int row = L >> 4, sl = L & 15;
            gld_lds16(Vh + (size_t)row * 2048 + kv0 + ((sl ^ (row & 7)) << 3),
                      &Vlds[buf][chunk * 512]);
        }
    };

    int qbcur = qbA;
    int q0w = qbA * 128 + wave * 32;
    int tloc = 0;

    bf16x8 qf[2][4];
    auto loadQ = [&]() {
#pragma unroll
        for (int mi = 0; mi < 2; ++mi)
#pragma unroll
            for (int kc = 0; kc < 4; ++kc)
                qf[mi][kc] = *(const bf16x8*)&Qr[((size_t)h * 2048 + q0w + mi * 16 + laneR) * 128 + kc * 32 + laneK];
    };
    loadQ();

    f32x4 o[2][8] = {};
    float mrow[2][4], lrow[2][4];
#pragma unroll
    for (int mi = 0; mi < 2; ++mi)
#pragma unroll
        for (int rr = 0; rr < 4; ++rr) { mrow[mi][rr] = -1e30f; lrow[mi][rr] = 0.f; }

    stageK(0, 0);
    stageV(0, 0);
    __syncthreads();

    for (int g = 0; g < 17; ++g) {
        const int buf = g & 1;
        if (g < 16) {
            const int tn = (g + 1 <= qbA) ? (g + 1) : (g - qbA);
            stageK(tn * 128, buf ^ 1);
            stageV(tn * 128, buf ^ 1);
        }
        const int kv0 = tloc * 128;

        f32x4 sc[2][8] = {};
        __builtin_amdgcn_s_setprio(1);
#pragma unroll
        for (int kc = 0; kc < 4; ++kc) {
            bf16x8 kf[8];
#pragma unroll
            for (int j = 0; j < 8; ++j) {
                const int row = j * 16 + laneR;
                kf[j] = *(const bf16x8*)((const char*)Klds[buf] + row * 256 +
                                         ((kc * 64 + laneS * 16) ^ ((row & 7) << 4)));
            }
#pragma unroll
            for (int mi = 0; mi < 2; ++mi)
#pragma unroll
                for (int j = 0; j < 8; ++j)
                    sc[mi][j] = __builtin_amdgcn_mfma_f32_16x16x32_bf16(qf[mi][kc], kf[j], sc[mi][j], 0, 0, 0);
        }
        __builtin_amdgcn_s_setprio(0);

        if (tloc == qbcur) {
#pragma unroll
            for (int mi = 0; mi < 2; ++mi)
#pragma unroll
                for (int j = 0; j < 8; ++j)
#pragma unroll
                    for (int rr = 0; rr < 4; ++rr) {
                        const int qr = q0w + mi * 16 + rbase + rr;
                        const int kr = kv0 + j * 16 + laneR;
                        if (kr > qr) sc[mi][j][rr] = -1e30f;
                    }
        }

#pragma unroll
        for (int mi = 0; mi < 2; ++mi) {
#pragma unroll
            for (int rr = 0; rr < 4; ++rr) {
                float v = sc[mi][0][rr];
#pragma unroll
                for (int j = 1; j < 8; ++j) v = fmaxf(v, sc[mi][j][rr]);
                v = fmaxf(v, __shfl_xor(v, 1, 64));
                v = fmaxf(v, __shfl_xor(v, 2, 64));
                v = fmaxf(v, __shfl_xor(v, 4, 64));
                v = fmaxf(v, __shfl_xor(v, 8, 64));
                float m0 = mrow[mi][rr];
                if (v - m0 > 8.0f) {
                    const float fac = __builtin_exp2f(m0 - v);
                    mrow[mi][rr] = v;
                    m0 = v;
                    lrow[mi][rr] *= fac;
#pragma unroll
                    for (int j = 0; j < 8; ++j) o[mi][j][rr] *= fac;
                }
                float rs = 0.f;
#pragma unroll
                for (int j = 0; j < 8; ++j) {
                    const float p = __builtin_exp2f(sc[mi][j][rr] - m0);
                    sc[mi][j][rr] = p;
                    rs += p;
                }
                rs += __shfl_xor(rs, 1, 64);
                rs += __shfl_xor(rs, 2, 64);
                rs += __shfl_xor(rs, 4, 64);
                rs += __shfl_xor(rs, 8, 64);
                lrow[mi][rr] += rs;
            }
        }

#pragma unroll
        for (int hf = 0; hf < 2; ++hf) {
#pragma unroll
            for (int mi = 0; mi < 2; ++mi)
#pragma unroll
                for (int j = 0; j < 4; ++j)
#pragma unroll
                    for (int rr = 0; rr < 4; ++rr) {
                        const int row = mi * 16 + rbase + rr;
                        *(bf16*)(Pw + row * 128 + ((j * 32 + laneR * 2) ^ ((row & 7) << 4))) =
                            (bf16)sc[mi][hf * 4 + j][rr];
                    }
            __builtin_amdgcn_s_setprio(1);
#pragma unroll
            for (int kc = 0; kc < 2; ++kc) {
                bf16x8 pf[2];
#pragma unroll
                for (int mi = 0; mi < 2; ++mi) {
                    const int row = mi * 16 + laneR;
                    pf[mi] = *(const bf16x8*)(Pw + row * 128 + ((kc * 64 + laneS * 16) ^ ((row & 7) << 4)));
                }
                const int kcg = hf * 2 + kc;
                bf16x8 vf[8];
#pragma unroll
                for (int j = 0; j < 8; ++j) {
                    const int row = j * 16 + laneR;
                    vf[j] = *(const bf16x8*)((const char*)Vlds[buf] + row * 256 +
                                             ((kcg * 64 + laneS * 16) ^ ((row & 7) << 4)));
                }
#pragma unroll
                for (int mi = 0; mi < 2; ++mi)
#pragma unroll
                    for (int j = 0; j < 8; ++j)
                        o[mi][j] = __builtin_amdgcn_mfma_f32_16x16x32_bf16(pf[mi], vf[j], o[mi][j], 0, 0, 0);
            }
            __builtin_amdgcn_s_setprio(0);
        }

        if (tloc == qbcur) {
#pragma unroll
            for (int mi = 0; mi < 2; ++mi) {
                float rinv[4];
#pragma unroll
                for (int rr = 0; rr < 4; ++rr) rinv[rr] = 1.0f / lrow[mi][rr];
#pragma unroll
                for (int j = 0; j < 8; ++j)
#pragma unroll
                    for (int rr = 0; rr < 4; ++rr) {
                        const size_t row = (size_t)q0w + mi * 16 + rbase + rr;
                        Aout[row * 4096 + h * 128 + j * 16 + laneR] = (bf16)(o[mi][j][rr] * rinv[rr]);
                    }
            }
            if (g < 16) {
                qbcur = qbB;
                q0w = qbB * 128 + wave * 32;
                tloc = 0;
                loadQ();
#pragma unroll
                for (int mi = 0; mi < 2; ++mi)
#pragma unroll
                    for (int rr = 0; rr < 4; ++rr) { mrow[mi][rr] = -1e30f; lrow[mi][rr] = 0.f; }
#pragma unroll
                for (int mi = 0; mi < 2; ++mi)
#pragma unroll
                    for (int j = 0; j < 8; ++j)
                        o[mi][j] = f32x4{0.f, 0.f, 0.f, 0.f};
            }
        } else {
            ++tloc;
        }

        __syncthreads();
    }
}

// ---------------- launch ----------------
extern "C" void kernel_launch(void* const* d_in, const int* in_sizes, int n_in,
                              void* d_out, int out_size, void* d_ws, size_t ws_size,
                              hipStream_t stream) {
    const float* hidden = (const float*)d_in[0];
    const float* Wq = (const float*)d_in[1];
    const float* Wk = (const float*)d_in[2];
    const float* Wv = (const float*)d_in[3];
    const float* Wo = (const float*)d_in[4];
    float* out = (float*)d_out;
    char* ws = (char*)d_ws;

    // workspace layout (bytes):
    bf16* hs = (bf16*)(ws + 0);                 // [2048][4096]        16 MiB
    bf16* Wb = (bf16*)(ws + 16777216);          // [10240][4096]       80 MiB (Wq|Wk|Wv|Wo)
    bf16* Cq = (bf16*)(ws + 100663296);         // [2048][6144]        24 MiB
    bf16* Qr = (bf16*)(ws + 125829120);         // [32][2048][128]     16 MiB
    bf16* Kr = (bf16*)(ws + 142606336);         // [8][2048][128]       4 MiB
    bf16* Vt = (bf16*)(ws + 146800640);         // [8][128][2048]       4 MiB
    bf16* At = (bf16*)(ws + 150994944);         // [2048][4096]        16 MiB
    (void)ws_size; (void)in_sizes; (void)n_in; (void)out_size;

    // 1. casts
    cvt4_kernel<<<8192, 256, 0, stream>>>((const float4*)hidden, (ushort4*)hs, 2097152);
    cvt4_kernel<<<16384, 256, 0, stream>>>((const float4*)Wq, (ushort4*)(Wb + 0), 4194304);
    cvt4_kernel<<<4096, 256, 0, stream>>>((const float4*)Wk, (ushort4*)(Wb + 16777216), 1048576);
    cvt4_kernel<<<4096, 256, 0, stream>>>((const float4*)Wv, (ushort4*)(Wb + 20971520), 1048576);
    cvt4_kernel<<<16384, 256, 0, stream>>>((const float4*)Wo, (ushort4*)(Wb + 25165824), 4194304);

    // 2. fused QKV projection: [2048,6144] = hs @ Wqkv^T  (128x384 tiles -> 256 blocks)
    gemm8p_kernel<384, false><<<dim3(16, 16), 512, 0, stream>>>(hs, Wb, Cq, 2048, 6144, 4096);

    // 3. RoPE (+transpose to [h][s][d]); q pre-scaled by log2e/sqrt(D)
    rope_qk_kernel<<<20480, 256, 0, stream>>>(Cq, Qr, Kr);

    // 4. V transpose -> [hkv][d][s]
    transpose_v_kernel<<<256, 256, 0, stream>>>(Cq, Vt);

    // 5. causal GQA flash attention -> At [2048][4096] bf16 (256 equal-work blocks)
    flash_attn_kernel<<<256, 256, 0, stream>>>(Qr, Kr, Vt, At);

    // 6. output projection: out = At @ Wo^T (fp32 out)  (128x256 tiles -> 256 blocks)
    gemm8p_kernel<256, true><<<dim3(16, 16), 512, 0, stream>>>(At, Wb + 25165824, out, 2048, 4096, 4096);
}